// Round 6
// baseline (189.890 us; speedup 1.0000x reference)
//
#include <hip/hip_runtime.h>
#include <hip/hip_bf16.h>

// KascadeReuseAttention  B=1, S=2048, DM=1024, H=16, D=64, T=16, NA=3
// Round-22 (base r21 = 150.0us): single change — attn cross-lane ops
// moved off the DS pipe (shfl_xor -> DPP), WITHOUT touching the LDS
// arrays / load-address dependences that anchor hoisting (r18 lesson).
//   - phase-2 quad butterfly xor1/xor2 -> DPP quad_perm (bit-identical).
//   - softmax: keep xor32/xor16 shfl; within-16 levels via DPP
//     row_mirror/row_half_mirror/quad_perm (exact, each elem once);
//     serial cross-lane chain ~500 -> ~200cyc.
//   - phase-4 remap tq=lane&3, dd=lane>>2 (same 4x128B/round coalescing;
//     ts reads preserved): final reduce intra-quad DPP; weights via
//     permuted ww store + 4x ds_read_b128 (was 16 scalar reads).
// DS ops/wave ~76 -> ~41. qs/ts kept verbatim (liveness anchors).
// History: r18 DS-diet regressed (193us: ts/qs removal -> VGPR 40 ->
// loads not hoisted). r20 qkv 2-phase dbuf (+1.3). r21 XCD remap (~0,
// kept). Known budget: ~45us ws-poison fill (immovable) + ~35 attn +
// ~23 qkv + ~10 prep + out + gaps.

#define S_LEN 2048
#define DM 1024
#define NH 16
#define HD 64

typedef __bf16 bf16x8 __attribute__((ext_vector_type(8)));
typedef float f32x4 __attribute__((ext_vector_type(4)));

static __device__ __forceinline__ unsigned short f2bf(float f) {
    union { float f; unsigned int i; } un;
    un.f = f;
    unsigned int r = un.i + 0x7FFFu + ((un.i >> 16) & 1u);  // RNE
    return (unsigned short)(r >> 16);
}
static __device__ __forceinline__ float bfu2f(unsigned short u) {
    union { unsigned int i; float f; } un;
    un.i = ((unsigned int)u) << 16;
    return un.f;
}
static __device__ __forceinline__ float bflo(unsigned int u) {
    union { unsigned int i; float f; } un;
    un.i = u << 16;
    return un.f;
}
static __device__ __forceinline__ float bfhi(unsigned int u) {
    union { unsigned int i; float f; } un;
    un.i = u & 0xFFFF0000u;
    return un.f;
}

// DPP cross-lane (VALU, no DS). CTRL: 0xB1 quad_perm [1,0,3,2] (xor1),
// 0x4E quad_perm [2,3,0,1] (xor2), 0x140 row_mirror (i<->15-i within 16),
// 0x141 row_half_mirror (i<->7-i within 8).
template <int CTRL>
static __device__ __forceinline__ float qperm(float x) {
    return __int_as_float(__builtin_amdgcn_update_dpp(
        0, __float_as_int(x), CTRL, 0xF, 0xF, true));
}

// async global->LDS, 16 B per lane; LDS dest = uniform base + lane*16.
static __device__ __forceinline__ void gll16(const unsigned short* g,
                                             unsigned short* l) {
    __builtin_amdgcn_global_load_lds(
        (const __attribute__((address_space(1))) unsigned int*)(uintptr_t)g,
        (__attribute__((address_space(3))) unsigned int*)(uintptr_t)l,
        16, 0, 0);
}

// ---------------------------------------------------------------------------
// prep: blocks [0,4096) transpose W* fp32->bf16 [n][k]; blocks [4096,5120)
// convert x fp32->bf16.
// ---------------------------------------------------------------------------
__global__ __launch_bounds__(256) void prep(
    const float* __restrict__ x, unsigned short* __restrict__ xb,
    const float* __restrict__ W0, const float* __restrict__ W1,
    const float* __restrict__ W2, const float* __restrict__ W3,
    unsigned short* __restrict__ T0, unsigned short* __restrict__ T1,
    unsigned short* __restrict__ T2, unsigned short* __restrict__ T3) {
    const int bx = blockIdx.x;
    if (bx < 4096) {
        const int z = bx >> 10, rem = bx & 1023;
        const float* W = (z == 0) ? W0 : (z == 1) ? W1 : (z == 2) ? W2 : W3;
        unsigned short* T = (z == 0) ? T0 : (z == 1) ? T1 : (z == 2) ? T2 : T3;
        __shared__ float t[32][33];
        const int bn = (rem & 31) * 32, bk = (rem >> 5) * 32;
        const int tx = threadIdx.x & 31, ty = threadIdx.x >> 5;
        #pragma unroll
        for (int m = 0; m < 4; ++m)
            t[ty + m * 8][tx] = W[(size_t)(bk + ty + m * 8) * 1024 + bn + tx];
        __syncthreads();
        #pragma unroll
        for (int m = 0; m < 4; ++m)
            T[(size_t)(bn + ty + m * 8) * 1024 + bk + tx] = f2bf(t[tx][ty + m * 8]);
    } else {
        const int i = (bx - 4096) * 2048 + threadIdx.x * 8;
        float4 f0 = *(const float4*)(x + i);
        float4 f1 = *(const float4*)(x + i + 4);
        ushort4 o0, o1;
        o0.x = f2bf(f0.x); o0.y = f2bf(f0.y); o0.z = f2bf(f0.z); o0.w = f2bf(f0.w);
        o1.x = f2bf(f1.x); o1.y = f2bf(f1.y); o1.z = f2bf(f1.z); o1.w = f2bf(f1.w);
        *(ushort4*)(xb + i) = o0;
        *(ushort4*)(xb + i + 4) = o1;
    }
}

// ---------------------------------------------------------------------------
// QKV GEMM (r20-verbatim): 64x128 tile, BK=32, grid (24,32) = 768 blocks
// (3/CU), GLL width-16 staging, 2-phase double-buffered. Fused RoPE
// epilogue, head-major bf16 out [H][S][64].
// ---------------------------------------------------------------------------
__global__ __launch_bounds__(256) void gemm_qkv(
    const unsigned short* __restrict__ xb,
    const unsigned short* __restrict__ Wtq, const unsigned short* __restrict__ Wtk,
    const unsigned short* __restrict__ Wtv,
    unsigned short* __restrict__ qh, unsigned short* __restrict__ kh,
    unsigned short* __restrict__ vh,
    const float* __restrict__ cs, const float* __restrict__ sn) {
    __shared__ __align__(16) unsigned short Al[2][64 * 32];
    __shared__ __align__(16) unsigned short Bl[2][128 * 32];
    const int tid = threadIdx.x;
    const int nb = blockIdx.x >> 3;
    const unsigned short* __restrict__ Bt = (nb == 0) ? Wtq : (nb == 1) ? Wtk : Wtv;
    unsigned short* __restrict__ OUT = (nb == 0) ? qh : (nb == 1) ? kh : vh;
    const int col0 = (blockIdx.x & 7) * 128;
    const int row0 = blockIdx.y * 64;
    const int lane = tid & 63, wvi = tid >> 6;
    const int wr = (wvi >> 1) * 32, wc = (wvi & 1) * 64;
    const int l15 = lane & 15, quad = lane >> 4;

    const int grow = lane >> 2;            // 0..15
    const int gkc = (lane & 3) * 8;        // element offset within row
    const unsigned short* gA = xb + (size_t)(row0 + wvi * 16 + grow) * 1024 + gkc;
    const unsigned short* gB = Bt + (size_t)(col0 + wvi * 32 + grow) * 1024 + gkc;
    const int lAo = (wvi * 16) * 32;       // wave-uniform offsets in a buffer
    const int lBo = (wvi * 32) * 32;

    f32x4 acc[2][4] = {};
    // prologue: stage tile 0 into buf 0
    gll16(gA, Al[0] + lAo);
    gll16(gB, Bl[0] + lBo);
    gll16(gB + 16 * 1024, Bl[0] + lBo + 16 * 32);
    __syncthreads();                        // buf0 landed (vmcnt0 + barrier)
    for (int it = 0; it < 32; ++it) {
        const int cur = it & 1;
        if (it < 31) {                      // issue next-tile loads first
            const int k1 = (it + 1) * 32;
            gll16(gA + k1, Al[cur ^ 1] + lAo);
            gll16(gB + k1, Bl[cur ^ 1] + lBo);
            gll16(gB + 16 * 1024 + k1, Bl[cur ^ 1] + lBo + 16 * 32);
        }
        bf16x8 af[2], bfr[4];
        #pragma unroll
        for (int i = 0; i < 2; ++i)
            af[i] = *(const bf16x8*)&Al[cur][(wr + i * 16 + l15) * 32 + quad * 8];
        #pragma unroll
        for (int j = 0; j < 4; ++j)
            bfr[j] = *(const bf16x8*)&Bl[cur][(wc + j * 16 + l15) * 32 + quad * 8];
        #pragma unroll
        for (int i = 0; i < 2; ++i)
            #pragma unroll
            for (int j = 0; j < 4; ++j)
                acc[i][j] = __builtin_amdgcn_mfma_f32_16x16x32_bf16(
                    af[i], bfr[j], acc[i][j], 0, 0, 0);
        __syncthreads();   // drains next-tile GLLs (flew under ds_read+MFMA)
    }

    // epilogue: wave's 64 cols = one head; fused RoPE; head-major store
    const int hh = ((blockIdx.x & 7) << 1) + (wc >> 6);
    const bool dorope = (nb != 2);
    #pragma unroll
    for (int i = 0; i < 2; ++i) {
        const int rowb = row0 + wr + i * 16 + quad * 4;
        #pragma unroll
        for (int r = 0; r < 4; ++r) {
            const int s = rowb + r;
            float v0 = acc[i][0][r], v1 = acc[i][1][r];
            float v2 = acc[i][2][r], v3 = acc[i][3][r];
            if (dorope) {
                float c0 = cs[s * 32 + l15],      s0 = sn[s * 32 + l15];
                float c1 = cs[s * 32 + 16 + l15], s1 = sn[s * 32 + 16 + l15];
                float lo0 = v0 * c0 - v2 * s0;
                float hi0 = v2 * c0 + v0 * s0;
                float lo1 = v1 * c1 - v3 * s1;
                float hi1 = v3 * c1 + v1 * s1;
                v0 = lo0; v1 = lo1; v2 = hi0; v3 = hi1;
            }
            unsigned short* op = OUT + (size_t)hh * (S_LEN * 64) + (size_t)s * 64 + l15;
            op[0]  = f2bf(v0);
            op[16] = f2bf(v1);
            op[32] = f2bf(v2);
            op[48] = f2bf(v3);
        }
    }
}

// ---------------------------------------------------------------------------
// Attention (r22): r21 structure (XCD remap kept); qs/ts LDS + load
// addressing verbatim (hoisting anchors). Cross-lane reductions moved to
// DPP; phase-4 lanes (tq=lane&3, dd=lane>>2) + permuted ww weights.
// ---------------------------------------------------------------------------
__global__ __launch_bounds__(256) void attn_kernel(
    const unsigned short* __restrict__ qh, const unsigned short* __restrict__ kh,
    const unsigned short* __restrict__ vh, const int* __restrict__ anc,
    unsigned short* __restrict__ att) {
    __shared__ __align__(16) float qs[4][64];
    __shared__ __align__(16) int   ts[4][64];
    __shared__ __align__(16) float ws[4][64];
    __shared__ __align__(16) float ww[4][64];
    const int w4 = threadIdx.x >> 6;
    const int lane = threadIdx.x & 63;
    // XCD-aware remap (bijective over 8192 blocks): each XCD owns 2 heads.
    const int bid = blockIdx.x;
    const int xcd = bid & 7;
    const int idx = bid >> 3;                  // 0..1023
    const int h   = (xcd << 1) | (idx >> 9);   // 2 heads per XCD
    const int qi  = ((idx & 511) << 2) + w4;   // 512 q-blocks per head
    const size_t hb = (size_t)h * (S_LEN * 64);

    const float q_own = bfu2f(qh[hb + (size_t)qi * 64 + lane]);
    const int slot = lane >> 4;
    const int tile = (slot < 3) ? anc[((size_t)h * S_LEN + qi) * 3 + slot]
                                : (qi >> 4);
    const int tok_own = tile * 16 + (lane & 15);
    qs[w4][lane] = q_own;
    ts[w4][lane] = tok_own;

    const int c = lane & 3;
    const int t = lane >> 2;
    float qv[16];
    #pragma unroll
    for (int r = 0; r < 4; ++r) {
        float4 f = *(const float4*)&qs[w4][c * 16 + r * 4];
        qv[r * 4 + 0] = f.x; qv[r * 4 + 1] = f.y;
        qv[r * 4 + 2] = f.z; qv[r * 4 + 3] = f.w;
    }

    #pragma unroll
    for (int p = 0; p < 4; ++p) {
        const int tk = ts[w4][p * 16 + t];
        const unsigned short* kp = kh + hb + (size_t)tk * 64 + c * 16;
        const uint4 k0 = *(const uint4*)kp;
        const uint4 k1 = *(const uint4*)(kp + 8);
        float part;
        part = bflo(k0.x) * qv[0];
        part = fmaf(bfhi(k0.x), qv[1], part);
        part = fmaf(bflo(k0.y), qv[2], part);
        part = fmaf(bfhi(k0.y), qv[3], part);
        part = fmaf(bflo(k0.z), qv[4], part);
        part = fmaf(bfhi(k0.z), qv[5], part);
        part = fmaf(bflo(k0.w), qv[6], part);
        part = fmaf(bfhi(k0.w), qv[7], part);
        part = fmaf(bflo(k1.x), qv[8], part);
        part = fmaf(bfhi(k1.x), qv[9], part);
        part = fmaf(bflo(k1.y), qv[10], part);
        part = fmaf(bfhi(k1.y), qv[11], part);
        part = fmaf(bflo(k1.z), qv[12], part);
        part = fmaf(bfhi(k1.z), qv[13], part);
        part = fmaf(bflo(k1.w), qv[14], part);
        part = fmaf(bfhi(k1.w), qv[15], part);
        // quad butterfly via DPP (bit-identical to shfl_xor 1,2)
        part += qperm<0xB1>(part);
        part += qperm<0x4E>(part);
        if (c == 0) ws[w4][p * 16 + t] = part;
    }

    float logit = ws[w4][lane];
    const bool fut = tok_own > qi;
    logit = fut ? -1e30f : logit * 0.125f;

    // max: xor32/xor16 via shfl; within-16 via DPP mirror tree (exact)
    float m = logit;
    m = fmaxf(m, __shfl_xor(m, 32, 64));
    m = fmaxf(m, __shfl_xor(m, 16, 64));
    m = fmaxf(m, qperm<0x140>(m));   // row_mirror
    m = fmaxf(m, qperm<0x141>(m));   // row_half_mirror
    m = fmaxf(m, qperm<0x4E>(m));
    m = fmaxf(m, qperm<0xB1>(m));
    const float e = fut ? 0.f : __expf(logit - m);
    float ssum = e;
    ssum += __shfl_xor(ssum, 32, 64);
    ssum += __shfl_xor(ssum, 16, 64);
    ssum += qperm<0x140>(ssum);
    ssum += qperm<0x141>(ssum);
    ssum += qperm<0x4E>(ssum);
    ssum += qperm<0xB1>(ssum);
    const float wgt = e / ssum;
    ws[w4][lane] = wgt;                       // (kept: cheap, aids debug)
    ww[w4][(lane & 3) * 16 + (lane >> 2)] = wgt;   // permuted for phase 4

    // phase 4: weighted V sum. lane = (tq=lane&3, dd=lane>>2); round r
    // covers tokens r*4+tq (4 rows x 128B per round, same coalescing);
    // ts reads preserved (hoisting anchor); weights via 4x ds_read_b128.
    const int tq = lane & 3;
    const int dd = lane >> 2;
    const unsigned short* vbase = vh + hb + dd * 4;
    f32x4 wv[4];
    #pragma unroll
    for (int r4 = 0; r4 < 4; ++r4)
        wv[r4] = *(const f32x4*)&ww[w4][tq * 16 + r4 * 4];
    float a0 = 0.f, a1 = 0.f, a2 = 0.f, a3 = 0.f;
    #pragma unroll
    for (int r = 0; r < 16; ++r) {
        const int kk = r * 4 + tq;
        const int tok = ts[w4][kk];
        const uint2 vv = *(const uint2*)(vbase + (size_t)tok * 64);
        const float w = wv[r >> 2][r & 3];
        a0 = fmaf(w, bflo(vv.x), a0);
        a1 = fmaf(w, bfhi(vv.x), a1);
        a2 = fmaf(w, bflo(vv.y), a2);
        a3 = fmaf(w, bfhi(vv.y), a3);
    }
    // cross-token reduce is intra-quad: DPP butterfly (exact)
    a0 += qperm<0xB1>(a0); a0 += qperm<0x4E>(a0);
    a1 += qperm<0xB1>(a1); a1 += qperm<0x4E>(a1);
    a2 += qperm<0xB1>(a2); a2 += qperm<0x4E>(a2);
    a3 += qperm<0xB1>(a3); a3 += qperm<0x4E>(a3);
    if (tq == 0) {
        ushort4 o;
        o.x = f2bf(a0); o.y = f2bf(a1); o.z = f2bf(a2); o.w = f2bf(a3);
        *(ushort4*)&att[(size_t)qi * DM + h * HD + dd * 4] = o;
    }
}

// ---------------------------------------------------------------------------
// Out GEMM (r16-verbatim): 64x64 tile, grid (16,32) = 512 blocks = 2/CU.
// Wave tile 32x32; 2 GLL + 4 MFMA per wave per K-iter.
// ---------------------------------------------------------------------------
__global__ __launch_bounds__(256) void gemm_out(
    const unsigned short* __restrict__ A, const unsigned short* __restrict__ Bt,
    float* __restrict__ C) {
    __shared__ __align__(16) unsigned short Al[64 * 32];
    __shared__ __align__(16) unsigned short Bl[64 * 32];
    const int tid = threadIdx.x;
    const int col0 = blockIdx.x * 64;
    const int row0 = blockIdx.y * 64;
    const int lane = tid & 63, wvi = tid >> 6;
    const int wr = (wvi >> 1) * 32, wc = (wvi & 1) * 32;
    const int l15 = lane & 15, quad = lane >> 4;

    const int grow = lane >> 2;
    const int gkc = (lane & 3) * 8;
    const unsigned short* gA = A + (size_t)(row0 + wvi * 16 + grow) * 1024 + gkc;
    const unsigned short* gB = Bt + (size_t)(col0 + wvi * 16 + grow) * 1024 + gkc;
    unsigned short* lA = Al + (wvi * 16) * 32;   // wave-uniform
    unsigned short* lB = Bl + (wvi * 16) * 32;

    f32x4 acc[2][2] = {};
    for (int k0 = 0; k0 < 1024; k0 += 32) {
        __syncthreads();
        gll16(gA + k0, lA);                       // A: 64 rows total
        gll16(gB + k0, lB);                       // B: 64 rows total
        __syncthreads();
        bf16x8 af[2], bfr[2];
        #pragma unroll
        for (int i = 0; i < 2; ++i)
            af[i] = *(const bf16x8*)&Al[(wr + i * 16 + l15) * 32 + quad * 8];
        #pragma unroll
        for (int j = 0; j < 2; ++j)
            bfr[j] = *(const bf16x8*)&Bl[(wc + j * 16 + l15) * 32 + quad * 8];
        #pragma unroll
        for (int i = 0; i < 2; ++i)
            #pragma unroll
            for (int j = 0; j < 2; ++j)
                acc[i][j] = __builtin_amdgcn_mfma_f32_16x16x32_bf16(
                    af[i], bfr[j], acc[i][j], 0, 0, 0);
    }
    #pragma unroll
    for (int i = 0; i < 2; ++i) {
        const int rowb = row0 + wr + i * 16 + quad * 4;
        #pragma unroll
        for (int r = 0; r < 4; ++r) {
            float* crow = C + (size_t)(rowb + r) * 1024 + col0 + wc;
            #pragma unroll
            for (int j = 0; j < 2; ++j)
                crow[j * 16 + l15] = acc[i][j][r];
        }
    }
}

// ---------------------------------------------------------------------------
extern "C" void kernel_launch(void* const* d_in, const int* in_sizes, int n_in,
                              void* d_out, int out_size, void* d_ws, size_t ws_size,
                              hipStream_t stream) {
    const float* x   = (const float*)d_in[0];
    const float* Wq  = (const float*)d_in[1];
    const float* Wk  = (const float*)d_in[2];
    const float* Wv  = (const float*)d_in[3];
    const float* Wo  = (const float*)d_in[4];
    const float* cs  = (const float*)d_in[5];
    const float* sn  = (const float*)d_in[6];
    const int*   anc = (const int*)d_in[7];
    float* out = (float*)d_out;

    unsigned short* xb  = (unsigned short*)d_ws;
    unsigned short* Wtq = xb  + (size_t)2048 * 1024;
    unsigned short* Wtk = Wtq + (size_t)1024 * 1024;
    unsigned short* Wtv = Wtk + (size_t)1024 * 1024;
    unsigned short* Wto = Wtv + (size_t)1024 * 1024;
    unsigned short* qh  = Wto + (size_t)1024 * 1024;   // [H][S][64]
    unsigned short* kh  = qh  + (size_t)2048 * 1024;
    unsigned short* vh  = kh  + (size_t)2048 * 1024;
    unsigned short* att = vh  + (size_t)2048 * 1024;   // [S][H*D]

    prep<<<5120, 256, 0, stream>>>(x, xb, Wq, Wk, Wv, Wo, Wtq, Wtk, Wtv, Wto);
    gemm_qkv<<<dim3(24, 32), 256, 0, stream>>>(xb, Wtq, Wtk, Wtv,
                                               qh, kh, vh, cs, sn);
    attn_kernel<<<(S_LEN * NH) / 4, 256, 0, stream>>>(qh, kh, vh, anc, att);
    gemm_out<<<dim3(16, 32), 256, 0, stream>>>(att, Wto, out);
}

// Round 8
// 150.464 us; speedup vs baseline: 1.2620x; 1.2620x over previous
//
#include <hip/hip_runtime.h>
#include <hip/hip_bf16.h>

// KascadeReuseAttention  B=1, S=2048, DM=1024, H=16, D=64, T=16, NA=3
// Round-24 = r23 resubmitted verbatim (previous bench was an infra
// failure: "MI355X container failed twice" — no signal; same thing
// happened at r19->r20 and the verbatim resubmit succeeded).
// r22 (DPP cross-lane) REGRESSED to 190us with the SAME fingerprint as
// r18 (VGPR 40, VALUBusy 30%): update_dpp builtins -> low-liveness
// schedule -> K/V loads not hoisted -> exposed L2 latency. DPP is BANNED
// in attn; all cross-lane stays __shfl_xor.
// This round: attn r21-verbatim EXCEPT phase-4 LDS fetch vectorized:
// permuted copies tsq/wsq stored at production ([(L&3)*16+(L>>2)]), so
// phase 4 reads 4x int4 + 4x f32x4 (8 ds_read_b128) instead of 32 scalar
// reads. Lane mapping, V addresses, shfl trees, FLOP order unchanged.
// History: r18/r22 regressions (low-VGPR hoisting collapse), r20 qkv
// 2-phase dbuf (+1.3), r21 XCD head remap (~0, kept).
// Known budget: ~45us ws-poison fill (immovable) + ~35 attn + ~23 qkv +
// ~10 prep + out + gaps.

#define S_LEN 2048
#define DM 1024
#define NH 16
#define HD 64

typedef __bf16 bf16x8 __attribute__((ext_vector_type(8)));
typedef float f32x4 __attribute__((ext_vector_type(4)));

static __device__ __forceinline__ unsigned short f2bf(float f) {
    union { float f; unsigned int i; } un;
    un.f = f;
    unsigned int r = un.i + 0x7FFFu + ((un.i >> 16) & 1u);  // RNE
    return (unsigned short)(r >> 16);
}
static __device__ __forceinline__ float bfu2f(unsigned short u) {
    union { unsigned int i; float f; } un;
    un.i = ((unsigned int)u) << 16;
    return un.f;
}
static __device__ __forceinline__ float bflo(unsigned int u) {
    union { unsigned int i; float f; } un;
    un.i = u << 16;
    return un.f;
}
static __device__ __forceinline__ float bfhi(unsigned int u) {
    union { unsigned int i; float f; } un;
    un.i = u & 0xFFFF0000u;
    return un.f;
}

// async global->LDS, 16 B per lane; LDS dest = uniform base + lane*16.
static __device__ __forceinline__ void gll16(const unsigned short* g,
                                             unsigned short* l) {
    __builtin_amdgcn_global_load_lds(
        (const __attribute__((address_space(1))) unsigned int*)(uintptr_t)g,
        (__attribute__((address_space(3))) unsigned int*)(uintptr_t)l,
        16, 0, 0);
}

// ---------------------------------------------------------------------------
// prep: blocks [0,4096) transpose W* fp32->bf16 [n][k]; blocks [4096,5120)
// convert x fp32->bf16.
// ---------------------------------------------------------------------------
__global__ __launch_bounds__(256) void prep(
    const float* __restrict__ x, unsigned short* __restrict__ xb,
    const float* __restrict__ W0, const float* __restrict__ W1,
    const float* __restrict__ W2, const float* __restrict__ W3,
    unsigned short* __restrict__ T0, unsigned short* __restrict__ T1,
    unsigned short* __restrict__ T2, unsigned short* __restrict__ T3) {
    const int bx = blockIdx.x;
    if (bx < 4096) {
        const int z = bx >> 10, rem = bx & 1023;
        const float* W = (z == 0) ? W0 : (z == 1) ? W1 : (z == 2) ? W2 : W3;
        unsigned short* T = (z == 0) ? T0 : (z == 1) ? T1 : (z == 2) ? T2 : T3;
        __shared__ float t[32][33];
        const int bn = (rem & 31) * 32, bk = (rem >> 5) * 32;
        const int tx = threadIdx.x & 31, ty = threadIdx.x >> 5;
        #pragma unroll
        for (int m = 0; m < 4; ++m)
            t[ty + m * 8][tx] = W[(size_t)(bk + ty + m * 8) * 1024 + bn + tx];
        __syncthreads();
        #pragma unroll
        for (int m = 0; m < 4; ++m)
            T[(size_t)(bn + ty + m * 8) * 1024 + bk + tx] = f2bf(t[tx][ty + m * 8]);
    } else {
        const int i = (bx - 4096) * 2048 + threadIdx.x * 8;
        float4 f0 = *(const float4*)(x + i);
        float4 f1 = *(const float4*)(x + i + 4);
        ushort4 o0, o1;
        o0.x = f2bf(f0.x); o0.y = f2bf(f0.y); o0.z = f2bf(f0.z); o0.w = f2bf(f0.w);
        o1.x = f2bf(f1.x); o1.y = f2bf(f1.y); o1.z = f2bf(f1.z); o1.w = f2bf(f1.w);
        *(ushort4*)(xb + i) = o0;
        *(ushort4*)(xb + i + 4) = o1;
    }
}

// ---------------------------------------------------------------------------
// QKV GEMM (r20-verbatim): 64x128 tile, BK=32, grid (24,32) = 768 blocks
// (3/CU), GLL width-16 staging, 2-phase double-buffered. Fused RoPE
// epilogue, head-major bf16 out [H][S][64].
// ---------------------------------------------------------------------------
__global__ __launch_bounds__(256) void gemm_qkv(
    const unsigned short* __restrict__ xb,
    const unsigned short* __restrict__ Wtq, const unsigned short* __restrict__ Wtk,
    const unsigned short* __restrict__ Wtv,
    unsigned short* __restrict__ qh, unsigned short* __restrict__ kh,
    unsigned short* __restrict__ vh,
    const float* __restrict__ cs, const float* __restrict__ sn) {
    __shared__ __align__(16) unsigned short Al[2][64 * 32];
    __shared__ __align__(16) unsigned short Bl[2][128 * 32];
    const int tid = threadIdx.x;
    const int nb = blockIdx.x >> 3;
    const unsigned short* __restrict__ Bt = (nb == 0) ? Wtq : (nb == 1) ? Wtk : Wtv;
    unsigned short* __restrict__ OUT = (nb == 0) ? qh : (nb == 1) ? kh : vh;
    const int col0 = (blockIdx.x & 7) * 128;
    const int row0 = blockIdx.y * 64;
    const int lane = tid & 63, wvi = tid >> 6;
    const int wr = (wvi >> 1) * 32, wc = (wvi & 1) * 64;
    const int l15 = lane & 15, quad = lane >> 4;

    const int grow = lane >> 2;            // 0..15
    const int gkc = (lane & 3) * 8;        // element offset within row
    const unsigned short* gA = xb + (size_t)(row0 + wvi * 16 + grow) * 1024 + gkc;
    const unsigned short* gB = Bt + (size_t)(col0 + wvi * 32 + grow) * 1024 + gkc;
    const int lAo = (wvi * 16) * 32;       // wave-uniform offsets in a buffer
    const int lBo = (wvi * 32) * 32;

    f32x4 acc[2][4] = {};
    // prologue: stage tile 0 into buf 0
    gll16(gA, Al[0] + lAo);
    gll16(gB, Bl[0] + lBo);
    gll16(gB + 16 * 1024, Bl[0] + lBo + 16 * 32);
    __syncthreads();                        // buf0 landed (vmcnt0 + barrier)
    for (int it = 0; it < 32; ++it) {
        const int cur = it & 1;
        if (it < 31) {                      // issue next-tile loads first
            const int k1 = (it + 1) * 32;
            gll16(gA + k1, Al[cur ^ 1] + lAo);
            gll16(gB + k1, Bl[cur ^ 1] + lBo);
            gll16(gB + 16 * 1024 + k1, Bl[cur ^ 1] + lBo + 16 * 32);
        }
        bf16x8 af[2], bfr[4];
        #pragma unroll
        for (int i = 0; i < 2; ++i)
            af[i] = *(const bf16x8*)&Al[cur][(wr + i * 16 + l15) * 32 + quad * 8];
        #pragma unroll
        for (int j = 0; j < 4; ++j)
            bfr[j] = *(const bf16x8*)&Bl[cur][(wc + j * 16 + l15) * 32 + quad * 8];
        #pragma unroll
        for (int i = 0; i < 2; ++i)
            #pragma unroll
            for (int j = 0; j < 4; ++j)
                acc[i][j] = __builtin_amdgcn_mfma_f32_16x16x32_bf16(
                    af[i], bfr[j], acc[i][j], 0, 0, 0);
        __syncthreads();   // drains next-tile GLLs (flew under ds_read+MFMA)
    }

    // epilogue: wave's 64 cols = one head; fused RoPE; head-major store
    const int hh = ((blockIdx.x & 7) << 1) + (wc >> 6);
    const bool dorope = (nb != 2);
    #pragma unroll
    for (int i = 0; i < 2; ++i) {
        const int rowb = row0 + wr + i * 16 + quad * 4;
        #pragma unroll
        for (int r = 0; r < 4; ++r) {
            const int s = rowb + r;
            float v0 = acc[i][0][r], v1 = acc[i][1][r];
            float v2 = acc[i][2][r], v3 = acc[i][3][r];
            if (dorope) {
                float c0 = cs[s * 32 + l15],      s0 = sn[s * 32 + l15];
                float c1 = cs[s * 32 + 16 + l15], s1 = sn[s * 32 + 16 + l15];
                float lo0 = v0 * c0 - v2 * s0;
                float hi0 = v2 * c0 + v0 * s0;
                float lo1 = v1 * c1 - v3 * s1;
                float hi1 = v3 * c1 + v1 * s1;
                v0 = lo0; v1 = lo1; v2 = hi0; v3 = hi1;
            }
            unsigned short* op = OUT + (size_t)hh * (S_LEN * 64) + (size_t)s * 64 + l15;
            op[0]  = f2bf(v0);
            op[16] = f2bf(v1);
            op[32] = f2bf(v2);
            op[48] = f2bf(v3);
        }
    }
}

// ---------------------------------------------------------------------------
// Attention (r23): r21 structure verbatim (XCD remap, shfl trees, qs/ts
// anchors); ONLY phase-4 LDS fetch vectorized via permuted tsq/wsq copies
// read as ds_read_b128.
// ---------------------------------------------------------------------------
__global__ __launch_bounds__(256) void attn_kernel(
    const unsigned short* __restrict__ qh, const unsigned short* __restrict__ kh,
    const unsigned short* __restrict__ vh, const int* __restrict__ anc,
    unsigned short* __restrict__ att) {
    __shared__ __align__(16) float qs[4][64];
    __shared__ __align__(16) int   ts[4][64];
    __shared__ __align__(16) float ws[4][64];
    __shared__ __align__(16) int   tsq[4][64];   // permuted tokens
    __shared__ __align__(16) float wsq[4][64];   // permuted weights
    const int w4 = threadIdx.x >> 6;
    const int lane = threadIdx.x & 63;
    // XCD-aware remap (bijective over 8192 blocks): each XCD owns 2 heads.
    const int bid = blockIdx.x;
    const int xcd = bid & 7;
    const int idx = bid >> 3;                  // 0..1023
    const int h   = (xcd << 1) | (idx >> 9);   // 2 heads per XCD
    const int qi  = ((idx & 511) << 2) + w4;   // 512 q-blocks per head
    const size_t hb = (size_t)h * (S_LEN * 64);

    const float q_own = bfu2f(qh[hb + (size_t)qi * 64 + lane]);
    const int slot = lane >> 4;
    const int tile = (slot < 3) ? anc[((size_t)h * S_LEN + qi) * 3 + slot]
                                : (qi >> 4);
    const int tok_own = tile * 16 + (lane & 15);
    qs[w4][lane] = q_own;
    ts[w4][lane] = tok_own;
    tsq[w4][(lane & 3) * 16 + (lane >> 2)] = tok_own;   // permuted copy

    const int c = lane & 3;
    const int t = lane >> 2;
    float qv[16];
    #pragma unroll
    for (int r = 0; r < 4; ++r) {
        float4 f = *(const float4*)&qs[w4][c * 16 + r * 4];
        qv[r * 4 + 0] = f.x; qv[r * 4 + 1] = f.y;
        qv[r * 4 + 2] = f.z; qv[r * 4 + 3] = f.w;
    }

    #pragma unroll
    for (int p = 0; p < 4; ++p) {
        const int tk = ts[w4][p * 16 + t];
        const unsigned short* kp = kh + hb + (size_t)tk * 64 + c * 16;
        const uint4 k0 = *(const uint4*)kp;
        const uint4 k1 = *(const uint4*)(kp + 8);
        float part;
        part = bflo(k0.x) * qv[0];
        part = fmaf(bfhi(k0.x), qv[1], part);
        part = fmaf(bflo(k0.y), qv[2], part);
        part = fmaf(bfhi(k0.y), qv[3], part);
        part = fmaf(bflo(k0.z), qv[4], part);
        part = fmaf(bfhi(k0.z), qv[5], part);
        part = fmaf(bflo(k0.w), qv[6], part);
        part = fmaf(bfhi(k0.w), qv[7], part);
        part = fmaf(bflo(k1.x), qv[8], part);
        part = fmaf(bfhi(k1.x), qv[9], part);
        part = fmaf(bflo(k1.y), qv[10], part);
        part = fmaf(bfhi(k1.y), qv[11], part);
        part = fmaf(bflo(k1.z), qv[12], part);
        part = fmaf(bfhi(k1.z), qv[13], part);
        part = fmaf(bflo(k1.w), qv[14], part);
        part = fmaf(bfhi(k1.w), qv[15], part);
        part += __shfl_xor(part, 1, 64);
        part += __shfl_xor(part, 2, 64);
        if (c == 0) ws[w4][p * 16 + t] = part;
    }

    float logit = ws[w4][lane];
    const bool fut = tok_own > qi;
    logit = fut ? -1e30f : logit * 0.125f;

    float m = logit;
    #pragma unroll
    for (int off = 32; off >= 1; off >>= 1)
        m = fmaxf(m, __shfl_xor(m, off, 64));
    const float e = fut ? 0.f : __expf(logit - m);
    float ssum = e;
    #pragma unroll
    for (int off = 32; off >= 1; off >>= 1)
        ssum += __shfl_xor(ssum, off, 64);
    wsq[w4][(lane & 3) * 16 + (lane >> 2)] = e / ssum;  // permuted store

    // phase 4: vectorized weighted V sum (r17 lane mapping: tq=lane>>4,
    // dd=lane&15; round r covers tokens r*4..r*4+3). Tokens and weights
    // fetched via 8x ds_read_b128 from the permuted copies.
    const int tq = lane >> 4;
    const int dd = lane & 15;
    const unsigned short* vbase = vh + hb + dd * 4;
    const int4  ta0 = *(const int4*)&tsq[w4][tq * 16];
    const int4  ta1 = *(const int4*)&tsq[w4][tq * 16 + 4];
    const int4  ta2 = *(const int4*)&tsq[w4][tq * 16 + 8];
    const int4  ta3 = *(const int4*)&tsq[w4][tq * 16 + 12];
    const f32x4 wa0 = *(const f32x4*)&wsq[w4][tq * 16];
    const f32x4 wa1 = *(const f32x4*)&wsq[w4][tq * 16 + 4];
    const f32x4 wa2 = *(const f32x4*)&wsq[w4][tq * 16 + 8];
    const f32x4 wa3 = *(const f32x4*)&wsq[w4][tq * 16 + 12];
    int toks[16];
    toks[0] = ta0.x;  toks[1] = ta0.y;  toks[2]  = ta0.z;  toks[3]  = ta0.w;
    toks[4] = ta1.x;  toks[5] = ta1.y;  toks[6]  = ta1.z;  toks[7]  = ta1.w;
    toks[8] = ta2.x;  toks[9] = ta2.y;  toks[10] = ta2.z;  toks[11] = ta2.w;
    toks[12] = ta3.x; toks[13] = ta3.y; toks[14] = ta3.z;  toks[15] = ta3.w;
    float wts[16];
    wts[0] = wa0[0];  wts[1] = wa0[1];  wts[2]  = wa0[2];  wts[3]  = wa0[3];
    wts[4] = wa1[0];  wts[5] = wa1[1];  wts[6]  = wa1[2];  wts[7]  = wa1[3];
    wts[8] = wa2[0];  wts[9] = wa2[1];  wts[10] = wa2[2];  wts[11] = wa2[3];
    wts[12] = wa3[0]; wts[13] = wa3[1]; wts[14] = wa3[2];  wts[15] = wa3[3];
    float a0 = 0.f, a1 = 0.f, a2 = 0.f, a3 = 0.f;
    #pragma unroll
    for (int r = 0; r < 16; ++r) {
        const uint2 vv = *(const uint2*)(vbase + (size_t)toks[r] * 64);
        const float w = wts[r];
        a0 = fmaf(w, bflo(vv.x), a0);
        a1 = fmaf(w, bfhi(vv.x), a1);
        a2 = fmaf(w, bflo(vv.y), a2);
        a3 = fmaf(w, bfhi(vv.y), a3);
    }
    a0 += __shfl_xor(a0, 16, 64); a0 += __shfl_xor(a0, 32, 64);
    a1 += __shfl_xor(a1, 16, 64); a1 += __shfl_xor(a1, 32, 64);
    a2 += __shfl_xor(a2, 16, 64); a2 += __shfl_xor(a2, 32, 64);
    a3 += __shfl_xor(a3, 16, 64); a3 += __shfl_xor(a3, 32, 64);
    if (tq == 0) {
        ushort4 o;
        o.x = f2bf(a0); o.y = f2bf(a1); o.z = f2bf(a2); o.w = f2bf(a3);
        *(ushort4*)&att[(size_t)qi * DM + h * HD + dd * 4] = o;
    }
}

// ---------------------------------------------------------------------------
// Out GEMM (r16-verbatim): 64x64 tile, grid (16,32) = 512 blocks = 2/CU.
// Wave tile 32x32; 2 GLL + 4 MFMA per wave per K-iter.
// ---------------------------------------------------------------------------
__global__ __launch_bounds__(256) void gemm_out(
    const unsigned short* __restrict__ A, const unsigned short* __restrict__ Bt,
    float* __restrict__ C) {
    __shared__ __align__(16) unsigned short Al[64 * 32];
    __shared__ __align__(16) unsigned short Bl[64 * 32];
    const int tid = threadIdx.x;
    const int col0 = blockIdx.x * 64;
    const int row0 = blockIdx.y * 64;
    const int lane = tid & 63, wvi = tid >> 6;
    const int wr = (wvi >> 1) * 32, wc = (wvi & 1) * 32;
    const int l15 = lane & 15, quad = lane >> 4;

    const int grow = lane >> 2;
    const int gkc = (lane & 3) * 8;
    const unsigned short* gA = A + (size_t)(row0 + wvi * 16 + grow) * 1024 + gkc;
    const unsigned short* gB = Bt + (size_t)(col0 + wvi * 16 + grow) * 1024 + gkc;
    unsigned short* lA = Al + (wvi * 16) * 32;   // wave-uniform
    unsigned short* lB = Bl + (wvi * 16) * 32;

    f32x4 acc[2][2] = {};
    for (int k0 = 0; k0 < 1024; k0 += 32) {
        __syncthreads();
        gll16(gA + k0, lA);                       // A: 64 rows total
        gll16(gB + k0, lB);                       // B: 64 rows total
        __syncthreads();
        bf16x8 af[2], bfr[2];
        #pragma unroll
        for (int i = 0; i < 2; ++i)
            af[i] = *(const bf16x8*)&Al[(wr + i * 16 + l15) * 32 + quad * 8];
        #pragma unroll
        for (int j = 0; j < 2; ++j)
            bfr[j] = *(const bf16x8*)&Bl[(wc + j * 16 + l15) * 32 + quad * 8];
        #pragma unroll
        for (int i = 0; i < 2; ++i)
            #pragma unroll
            for (int j = 0; j < 2; ++j)
                acc[i][j] = __builtin_amdgcn_mfma_f32_16x16x32_bf16(
                    af[i], bfr[j], acc[i][j], 0, 0, 0);
    }
    #pragma unroll
    for (int i = 0; i < 2; ++i) {
        const int rowb = row0 + wr + i * 16 + quad * 4;
        #pragma unroll
        for (int r = 0; r < 4; ++r) {
            float* crow = C + (size_t)(rowb + r) * 1024 + col0 + wc;
            #pragma unroll
            for (int j = 0; j < 2; ++j)
                crow[j * 16 + l15] = acc[i][j][r];
        }
    }
}

// ---------------------------------------------------------------------------
extern "C" void kernel_launch(void* const* d_in, const int* in_sizes, int n_in,
                              void* d_out, int out_size, void* d_ws, size_t ws_size,
                              hipStream_t stream) {
    const float* x   = (const float*)d_in[0];
    const float* Wq  = (const float*)d_in[1];
    const float* Wk  = (const float*)d_in[2];
    const float* Wv  = (const float*)d_in[3];
    const float* Wo  = (const float*)d_in[4];
    const float* cs  = (const float*)d_in[5];
    const float* sn  = (const float*)d_in[6];
    const int*   anc = (const int*)d_in[7];
    float* out = (float*)d_out;

    unsigned short* xb  = (unsigned short*)d_ws;
    unsigned short* Wtq = xb  + (size_t)2048 * 1024;
    unsigned short* Wtk = Wtq + (size_t)1024 * 1024;
    unsigned short* Wtv = Wtk + (size_t)1024 * 1024;
    unsigned short* Wto = Wtv + (size_t)1024 * 1024;
    unsigned short* qh  = Wto + (size_t)1024 * 1024;   // [H][S][64]
    unsigned short* kh  = qh  + (size_t)2048 * 1024;
    unsigned short* vh  = kh  + (size_t)2048 * 1024;
    unsigned short* att = vh  + (size_t)2048 * 1024;   // [S][H*D]

    prep<<<5120, 256, 0, stream>>>(x, xb, Wq, Wk, Wv, Wo, Wtq, Wtk, Wtv, Wto);
    gemm_qkv<<<dim3(24, 32), 256, 0, stream>>>(xb, Wtq, Wtk, Wtv,
                                               qh, kh, vh, cs, sn);
    attn_kernel<<<(S_LEN * NH) / 4, 256, 0, stream>>>(qh, kh, vh, anc, att);
    gemm_out<<<dim3(16, 32), 256, 0, stream>>>(att, Wto, out);
}

// Round 9
// 146.471 us; speedup vs baseline: 1.2964x; 1.0273x over previous
//
#include <hip/hip_runtime.h>
#include <hip/hip_bf16.h>

// KascadeReuseAttention  B=1, S=2048, DM=1024, H=16, D=64, T=16, NA=3
// Round-25 (base r21/r24 = 150.0/150.5us). attn internals FROZEN at r21
// (5 attempts: r18/r22 regressed via VGPR-40 hoisting collapse; r17 ph4
// vec +3; r23/r24 tsq/wsq neutral -> dropped). This round, two non-attn
// changes:
//  1. prep W-transpose retiled 32x32 -> 64x64: store runs 64B->128B,
//     read runs 128B->256B, LDS [64][65] conflict-free; grid 5120->2048.
//  2. gemm_out 2-phase LDS double-buffer (r20 qkv pattern, proven):
//     stage tile t+1 before computing tile t, one barrier per K-step.
// History: r20 qkv dbuf (+1.3), r21 XCD head remap (~0, kept).
// Budget: ~45us ws-poison fill (immovable) + ~35 attn (frozen) +
// ~23 qkv + prep + out + gaps.

#define S_LEN 2048
#define DM 1024
#define NH 16
#define HD 64

typedef __bf16 bf16x8 __attribute__((ext_vector_type(8)));
typedef float f32x4 __attribute__((ext_vector_type(4)));

static __device__ __forceinline__ unsigned short f2bf(float f) {
    union { float f; unsigned int i; } un;
    un.f = f;
    unsigned int r = un.i + 0x7FFFu + ((un.i >> 16) & 1u);  // RNE
    return (unsigned short)(r >> 16);
}
static __device__ __forceinline__ float bfu2f(unsigned short u) {
    union { unsigned int i; float f; } un;
    un.i = ((unsigned int)u) << 16;
    return un.f;
}
static __device__ __forceinline__ float bflo(unsigned int u) {
    union { unsigned int i; float f; } un;
    un.i = u << 16;
    return un.f;
}
static __device__ __forceinline__ float bfhi(unsigned int u) {
    union { unsigned int i; float f; } un;
    un.i = u & 0xFFFF0000u;
    return un.f;
}

// async global->LDS, 16 B per lane; LDS dest = uniform base + lane*16.
static __device__ __forceinline__ void gll16(const unsigned short* g,
                                             unsigned short* l) {
    __builtin_amdgcn_global_load_lds(
        (const __attribute__((address_space(1))) unsigned int*)(uintptr_t)g,
        (__attribute__((address_space(3))) unsigned int*)(uintptr_t)l,
        16, 0, 0);
}

// ---------------------------------------------------------------------------
// prep (r25): blocks [0,1024) transpose W* fp32->bf16 [n][k] in 64x64
// tiles (256B read runs, 128B write runs, LDS [64][65] conflict-free);
// blocks [1024,2048) convert x fp32->bf16 (unchanged pattern).
// ---------------------------------------------------------------------------
__global__ __launch_bounds__(256) void prep(
    const float* __restrict__ x, unsigned short* __restrict__ xb,
    const float* __restrict__ W0, const float* __restrict__ W1,
    const float* __restrict__ W2, const float* __restrict__ W3,
    unsigned short* __restrict__ T0, unsigned short* __restrict__ T1,
    unsigned short* __restrict__ T2, unsigned short* __restrict__ T3) {
    const int bx = blockIdx.x;
    if (bx < 1024) {
        const int z = bx >> 8, rem = bx & 255;
        const float* W = (z == 0) ? W0 : (z == 1) ? W1 : (z == 2) ? W2 : W3;
        unsigned short* T = (z == 0) ? T0 : (z == 1) ? T1 : (z == 2) ? T2 : T3;
        __shared__ float t[64][65];
        const int bn = (rem & 15) * 64, bk = (rem >> 4) * 64;
        const int tx = threadIdx.x & 63, ty = threadIdx.x >> 6;  // ty 0..3
        #pragma unroll
        for (int m = 0; m < 16; ++m)            // 64 k-rows, 256B reads
            t[ty + m * 4][tx] = W[(size_t)(bk + ty + m * 4) * 1024 + bn + tx];
        __syncthreads();
        #pragma unroll
        for (int m = 0; m < 16; ++m)            // 64 n-rows, 128B writes
            T[(size_t)(bn + ty + m * 4) * 1024 + bk + tx] =
                f2bf(t[tx][ty + m * 4]);
    } else {
        const int i = (bx - 1024) * 2048 + threadIdx.x * 8;
        float4 f0 = *(const float4*)(x + i);
        float4 f1 = *(const float4*)(x + i + 4);
        ushort4 o0, o1;
        o0.x = f2bf(f0.x); o0.y = f2bf(f0.y); o0.z = f2bf(f0.z); o0.w = f2bf(f0.w);
        o1.x = f2bf(f1.x); o1.y = f2bf(f1.y); o1.z = f2bf(f1.z); o1.w = f2bf(f1.w);
        *(ushort4*)(xb + i) = o0;
        *(ushort4*)(xb + i + 4) = o1;
    }
}

// ---------------------------------------------------------------------------
// QKV GEMM (r20-verbatim): 64x128 tile, BK=32, grid (24,32) = 768 blocks
// (3/CU), GLL width-16 staging, 2-phase double-buffered. Fused RoPE
// epilogue, head-major bf16 out [H][S][64].
// ---------------------------------------------------------------------------
__global__ __launch_bounds__(256) void gemm_qkv(
    const unsigned short* __restrict__ xb,
    const unsigned short* __restrict__ Wtq, const unsigned short* __restrict__ Wtk,
    const unsigned short* __restrict__ Wtv,
    unsigned short* __restrict__ qh, unsigned short* __restrict__ kh,
    unsigned short* __restrict__ vh,
    const float* __restrict__ cs, const float* __restrict__ sn) {
    __shared__ __align__(16) unsigned short Al[2][64 * 32];
    __shared__ __align__(16) unsigned short Bl[2][128 * 32];
    const int tid = threadIdx.x;
    const int nb = blockIdx.x >> 3;
    const unsigned short* __restrict__ Bt = (nb == 0) ? Wtq : (nb == 1) ? Wtk : Wtv;
    unsigned short* __restrict__ OUT = (nb == 0) ? qh : (nb == 1) ? kh : vh;
    const int col0 = (blockIdx.x & 7) * 128;
    const int row0 = blockIdx.y * 64;
    const int lane = tid & 63, wvi = tid >> 6;
    const int wr = (wvi >> 1) * 32, wc = (wvi & 1) * 64;
    const int l15 = lane & 15, quad = lane >> 4;

    const int grow = lane >> 2;            // 0..15
    const int gkc = (lane & 3) * 8;        // element offset within row
    const unsigned short* gA = xb + (size_t)(row0 + wvi * 16 + grow) * 1024 + gkc;
    const unsigned short* gB = Bt + (size_t)(col0 + wvi * 32 + grow) * 1024 + gkc;
    const int lAo = (wvi * 16) * 32;       // wave-uniform offsets in a buffer
    const int lBo = (wvi * 32) * 32;

    f32x4 acc[2][4] = {};
    // prologue: stage tile 0 into buf 0
    gll16(gA, Al[0] + lAo);
    gll16(gB, Bl[0] + lBo);
    gll16(gB + 16 * 1024, Bl[0] + lBo + 16 * 32);
    __syncthreads();                        // buf0 landed (vmcnt0 + barrier)
    for (int it = 0; it < 32; ++it) {
        const int cur = it & 1;
        if (it < 31) {                      // issue next-tile loads first
            const int k1 = (it + 1) * 32;
            gll16(gA + k1, Al[cur ^ 1] + lAo);
            gll16(gB + k1, Bl[cur ^ 1] + lBo);
            gll16(gB + 16 * 1024 + k1, Bl[cur ^ 1] + lBo + 16 * 32);
        }
        bf16x8 af[2], bfr[4];
        #pragma unroll
        for (int i = 0; i < 2; ++i)
            af[i] = *(const bf16x8*)&Al[cur][(wr + i * 16 + l15) * 32 + quad * 8];
        #pragma unroll
        for (int j = 0; j < 4; ++j)
            bfr[j] = *(const bf16x8*)&Bl[cur][(wc + j * 16 + l15) * 32 + quad * 8];
        #pragma unroll
        for (int i = 0; i < 2; ++i)
            #pragma unroll
            for (int j = 0; j < 4; ++j)
                acc[i][j] = __builtin_amdgcn_mfma_f32_16x16x32_bf16(
                    af[i], bfr[j], acc[i][j], 0, 0, 0);
        __syncthreads();   // drains next-tile GLLs (flew under ds_read+MFMA)
    }

    // epilogue: wave's 64 cols = one head; fused RoPE; head-major store
    const int hh = ((blockIdx.x & 7) << 1) + (wc >> 6);
    const bool dorope = (nb != 2);
    #pragma unroll
    for (int i = 0; i < 2; ++i) {
        const int rowb = row0 + wr + i * 16 + quad * 4;
        #pragma unroll
        for (int r = 0; r < 4; ++r) {
            const int s = rowb + r;
            float v0 = acc[i][0][r], v1 = acc[i][1][r];
            float v2 = acc[i][2][r], v3 = acc[i][3][r];
            if (dorope) {
                float c0 = cs[s * 32 + l15],      s0 = sn[s * 32 + l15];
                float c1 = cs[s * 32 + 16 + l15], s1 = sn[s * 32 + 16 + l15];
                float lo0 = v0 * c0 - v2 * s0;
                float hi0 = v2 * c0 + v0 * s0;
                float lo1 = v1 * c1 - v3 * s1;
                float hi1 = v3 * c1 + v1 * s1;
                v0 = lo0; v1 = lo1; v2 = hi0; v3 = hi1;
            }
            unsigned short* op = OUT + (size_t)hh * (S_LEN * 64) + (size_t)s * 64 + l15;
            op[0]  = f2bf(v0);
            op[16] = f2bf(v1);
            op[32] = f2bf(v2);
            op[48] = f2bf(v3);
        }
    }
}

// ---------------------------------------------------------------------------
// Attention (r21-verbatim, FROZEN): one wave per (h,q); XCD-aware head
// remap; wave-private LDS slices; same-address broadcast ds_reads;
// phase-4 vectorized V gather (uint2 x16) with addresses from ts.
// ---------------------------------------------------------------------------
__global__ __launch_bounds__(256) void attn_kernel(
    const unsigned short* __restrict__ qh, const unsigned short* __restrict__ kh,
    const unsigned short* __restrict__ vh, const int* __restrict__ anc,
    unsigned short* __restrict__ att) {
    __shared__ __align__(16) float qs[4][64];
    __shared__ __align__(16) int   ts[4][64];
    __shared__ __align__(16) float ws[4][64];
    const int w4 = threadIdx.x >> 6;
    const int lane = threadIdx.x & 63;
    // XCD-aware remap (bijective over 8192 blocks): each XCD owns 2 heads.
    const int bid = blockIdx.x;
    const int xcd = bid & 7;
    const int idx = bid >> 3;                  // 0..1023
    const int h   = (xcd << 1) | (idx >> 9);   // 2 heads per XCD
    const int qi  = ((idx & 511) << 2) + w4;   // 512 q-blocks per head
    const size_t hb = (size_t)h * (S_LEN * 64);

    const float q_own = bfu2f(qh[hb + (size_t)qi * 64 + lane]);
    const int slot = lane >> 4;
    const int tile = (slot < 3) ? anc[((size_t)h * S_LEN + qi) * 3 + slot]
                                : (qi >> 4);
    const int tok_own = tile * 16 + (lane & 15);
    qs[w4][lane] = q_own;
    ts[w4][lane] = tok_own;

    const int c = lane & 3;
    const int t = lane >> 2;
    float qv[16];
    #pragma unroll
    for (int r = 0; r < 4; ++r) {
        float4 f = *(const float4*)&qs[w4][c * 16 + r * 4];
        qv[r * 4 + 0] = f.x; qv[r * 4 + 1] = f.y;
        qv[r * 4 + 2] = f.z; qv[r * 4 + 3] = f.w;
    }

    #pragma unroll
    for (int p = 0; p < 4; ++p) {
        const int tk = ts[w4][p * 16 + t];
        const unsigned short* kp = kh + hb + (size_t)tk * 64 + c * 16;
        const uint4 k0 = *(const uint4*)kp;
        const uint4 k1 = *(const uint4*)(kp + 8);
        float part;
        part = bflo(k0.x) * qv[0];
        part = fmaf(bfhi(k0.x), qv[1], part);
        part = fmaf(bflo(k0.y), qv[2], part);
        part = fmaf(bfhi(k0.y), qv[3], part);
        part = fmaf(bflo(k0.z), qv[4], part);
        part = fmaf(bfhi(k0.z), qv[5], part);
        part = fmaf(bflo(k0.w), qv[6], part);
        part = fmaf(bfhi(k0.w), qv[7], part);
        part = fmaf(bflo(k1.x), qv[8], part);
        part = fmaf(bfhi(k1.x), qv[9], part);
        part = fmaf(bflo(k1.y), qv[10], part);
        part = fmaf(bfhi(k1.y), qv[11], part);
        part = fmaf(bflo(k1.z), qv[12], part);
        part = fmaf(bfhi(k1.z), qv[13], part);
        part = fmaf(bflo(k1.w), qv[14], part);
        part = fmaf(bfhi(k1.w), qv[15], part);
        part += __shfl_xor(part, 1, 64);
        part += __shfl_xor(part, 2, 64);
        if (c == 0) ws[w4][p * 16 + t] = part;
    }

    float logit = ws[w4][lane];
    const bool fut = tok_own > qi;
    logit = fut ? -1e30f : logit * 0.125f;

    float m = logit;
    #pragma unroll
    for (int off = 32; off >= 1; off >>= 1)
        m = fmaxf(m, __shfl_xor(m, off, 64));
    const float e = fut ? 0.f : __expf(logit - m);
    float ssum = e;
    #pragma unroll
    for (int off = 32; off >= 1; off >>= 1)
        ssum += __shfl_xor(ssum, off, 64);
    ws[w4][lane] = e / ssum;

    // phase 4: vectorized weighted V sum.
    // lane -> (tq = token quad 0..3, dd = dim quad 0..15); round r covers
    // tokens r*4 .. r*4+3; each lane loads 4 bf16 dims (uint2, 8B).
    const int tq = lane >> 4;
    const int dd = lane & 15;
    const unsigned short* vbase = vh + hb + dd * 4;
    float a0 = 0.f, a1 = 0.f, a2 = 0.f, a3 = 0.f;
    #pragma unroll
    for (int r = 0; r < 16; ++r) {
        const int kk = r * 4 + tq;
        const int tok = ts[w4][kk];
        const uint2 vv = *(const uint2*)(vbase + (size_t)tok * 64);
        const float w = ws[w4][kk];
        a0 = fmaf(w, bflo(vv.x), a0);
        a1 = fmaf(w, bfhi(vv.x), a1);
        a2 = fmaf(w, bflo(vv.y), a2);
        a3 = fmaf(w, bfhi(vv.y), a3);
    }
    a0 += __shfl_xor(a0, 16, 64); a0 += __shfl_xor(a0, 32, 64);
    a1 += __shfl_xor(a1, 16, 64); a1 += __shfl_xor(a1, 32, 64);
    a2 += __shfl_xor(a2, 16, 64); a2 += __shfl_xor(a2, 32, 64);
    a3 += __shfl_xor(a3, 16, 64); a3 += __shfl_xor(a3, 32, 64);
    if (tq == 0) {
        ushort4 o;
        o.x = f2bf(a0); o.y = f2bf(a1); o.z = f2bf(a2); o.w = f2bf(a3);
        *(ushort4*)&att[(size_t)qi * DM + h * HD + dd * 4] = o;
    }
}

// ---------------------------------------------------------------------------
// Out GEMM (r25): 64x64 tile, grid (16,32) = 512 blocks = 2/CU, NOW
// 2-phase double-buffered (r20 qkv pattern): stage tile t+1 into buf^1
// before computing tile t; one barrier per K-step. Wave tile 32x32.
// ---------------------------------------------------------------------------
__global__ __launch_bounds__(256) void gemm_out(
    const unsigned short* __restrict__ A, const unsigned short* __restrict__ Bt,
    float* __restrict__ C) {
    __shared__ __align__(16) unsigned short Al[2][64 * 32];
    __shared__ __align__(16) unsigned short Bl[2][64 * 32];
    const int tid = threadIdx.x;
    const int col0 = blockIdx.x * 64;
    const int row0 = blockIdx.y * 64;
    const int lane = tid & 63, wvi = tid >> 6;
    const int wr = (wvi >> 1) * 32, wc = (wvi & 1) * 32;
    const int l15 = lane & 15, quad = lane >> 4;

    const int grow = lane >> 2;
    const int gkc = (lane & 3) * 8;
    const unsigned short* gA = A + (size_t)(row0 + wvi * 16 + grow) * 1024 + gkc;
    const unsigned short* gB = Bt + (size_t)(col0 + wvi * 16 + grow) * 1024 + gkc;
    const int lAo = (wvi * 16) * 32;       // wave-uniform offsets in a buffer
    const int lBo = (wvi * 16) * 32;

    f32x4 acc[2][2] = {};
    // prologue: stage tile 0 into buf 0
    gll16(gA, Al[0] + lAo);
    gll16(gB, Bl[0] + lBo);
    __syncthreads();                        // buf0 landed (vmcnt0 + barrier)
    for (int it = 0; it < 32; ++it) {
        const int cur = it & 1;
        if (it < 31) {                      // issue next-tile loads first
            const int k1 = (it + 1) * 32;
            gll16(gA + k1, Al[cur ^ 1] + lAo);
            gll16(gB + k1, Bl[cur ^ 1] + lBo);
        }
        bf16x8 af[2], bfr[2];
        #pragma unroll
        for (int i = 0; i < 2; ++i)
            af[i] = *(const bf16x8*)&Al[cur][(wr + i * 16 + l15) * 32 + quad * 8];
        #pragma unroll
        for (int j = 0; j < 2; ++j)
            bfr[j] = *(const bf16x8*)&Bl[cur][(wc + j * 16 + l15) * 32 + quad * 8];
        #pragma unroll
        for (int i = 0; i < 2; ++i)
            #pragma unroll
            for (int j = 0; j < 2; ++j)
                acc[i][j] = __builtin_amdgcn_mfma_f32_16x16x32_bf16(
                    af[i], bfr[j], acc[i][j], 0, 0, 0);
        __syncthreads();   // drains next-tile GLLs (flew under ds_read+MFMA)
    }
    #pragma unroll
    for (int i = 0; i < 2; ++i) {
        const int rowb = row0 + wr + i * 16 + quad * 4;
        #pragma unroll
        for (int r = 0; r < 4; ++r) {
            float* crow = C + (size_t)(rowb + r) * 1024 + col0 + wc;
            #pragma unroll
            for (int j = 0; j < 2; ++j)
                crow[j * 16 + l15] = acc[i][j][r];
        }
    }
}

// ---------------------------------------------------------------------------
extern "C" void kernel_launch(void* const* d_in, const int* in_sizes, int n_in,
                              void* d_out, int out_size, void* d_ws, size_t ws_size,
                              hipStream_t stream) {
    const float* x   = (const float*)d_in[0];
    const float* Wq  = (const float*)d_in[1];
    const float* Wk  = (const float*)d_in[2];
    const float* Wv  = (const float*)d_in[3];
    const float* Wo  = (const float*)d_in[4];
    const float* cs  = (const float*)d_in[5];
    const float* sn  = (const float*)d_in[6];
    const int*   anc = (const int*)d_in[7];
    float* out = (float*)d_out;

    unsigned short* xb  = (unsigned short*)d_ws;
    unsigned short* Wtq = xb  + (size_t)2048 * 1024;
    unsigned short* Wtk = Wtq + (size_t)1024 * 1024;
    unsigned short* Wtv = Wtk + (size_t)1024 * 1024;
    unsigned short* Wto = Wtv + (size_t)1024 * 1024;
    unsigned short* qh  = Wto + (size_t)1024 * 1024;   // [H][S][64]
    unsigned short* kh  = qh  + (size_t)2048 * 1024;
    unsigned short* vh  = kh  + (size_t)2048 * 1024;
    unsigned short* att = vh  + (size_t)2048 * 1024;   // [S][H*D]

    prep<<<2048, 256, 0, stream>>>(x, xb, Wq, Wk, Wv, Wo, Wtq, Wtk, Wtv, Wto);
    gemm_qkv<<<dim3(24, 32), 256, 0, stream>>>(xb, Wtq, Wtk, Wtv,
                                               qh, kh, vh, cs, sn);
    attn_kernel<<<(S_LEN * NH) / 4, 256, 0, stream>>>(qh, kh, vh, anc, att);
    gemm_out<<<dim3(16, 32), 256, 0, stream>>>(att, Wto, out);
}

// Round 10
// 145.372 us; speedup vs baseline: 1.3062x; 1.0076x over previous
//
#include <hip/hip_runtime.h>
#include <hip/hip_bf16.h>

// KascadeReuseAttention  B=1, S=2048, DM=1024, H=16, D=64, T=16, NA=3
// Round-26 (base r25 = 146.5us): single structural change — both GEMMs
// move from 2-phase/drain-0 to 3-buffer counted-vmcnt pipeline (T4):
//   body: ds_read buf[i%3]; GLL tile(i+2)->buf[(i+2)%3]; MFMA;
//         s_waitcnt vmcnt(3[qkv]/2[out]); s_barrier.
// The old __syncthreads drained the same-iter GLLs (flight covered only
// by ~300cyc of compute vs 500-900cyc latency — the m97 ~20% stall).
// Counted wait keeps tile i+2's loads in flight across the barrier.
// Safety: per-wave vmcnt(N)+barrier => all waves' tile-(i+1) loads
// landed; buf[(i+2)%3] overwrite protected by end-of-iter-(i-1) barrier;
// tails use vmcnt(0). attn frozen (r21); prep frozen (r25).
// History: r18/r22 attn regressions (VGPR-40 hoisting collapse; DPP
// banned), r20 qkv dbuf +1.3, r21 XCD remap ~0, r25 prep retile +
// out dbuf -3.5.
// Budget: ~45us ws-poison fill (immovable) + ~35 attn + qkv + prep +
// out + gaps.

#define S_LEN 2048
#define DM 1024
#define NH 16
#define HD 64

typedef __bf16 bf16x8 __attribute__((ext_vector_type(8)));
typedef float f32x4 __attribute__((ext_vector_type(4)));

static __device__ __forceinline__ unsigned short f2bf(float f) {
    union { float f; unsigned int i; } un;
    un.f = f;
    unsigned int r = un.i + 0x7FFFu + ((un.i >> 16) & 1u);  // RNE
    return (unsigned short)(r >> 16);
}
static __device__ __forceinline__ float bfu2f(unsigned short u) {
    union { unsigned int i; float f; } un;
    un.i = ((unsigned int)u) << 16;
    return un.f;
}
static __device__ __forceinline__ float bflo(unsigned int u) {
    union { unsigned int i; float f; } un;
    un.i = u << 16;
    return un.f;
}
static __device__ __forceinline__ float bfhi(unsigned int u) {
    union { unsigned int i; float f; } un;
    un.i = u & 0xFFFF0000u;
    return un.f;
}

// async global->LDS, 16 B per lane; LDS dest = uniform base + lane*16.
static __device__ __forceinline__ void gll16(const unsigned short* g,
                                             unsigned short* l) {
    __builtin_amdgcn_global_load_lds(
        (const __attribute__((address_space(1))) unsigned int*)(uintptr_t)g,
        (__attribute__((address_space(3))) unsigned int*)(uintptr_t)l,
        16, 0, 0);
}

// ---------------------------------------------------------------------------
// prep (r25-verbatim): blocks [0,1024) transpose W* fp32->bf16 [n][k] in
// 64x64 tiles (LDS [64][65]); blocks [1024,2048) convert x fp32->bf16.
// ---------------------------------------------------------------------------
__global__ __launch_bounds__(256) void prep(
    const float* __restrict__ x, unsigned short* __restrict__ xb,
    const float* __restrict__ W0, const float* __restrict__ W1,
    const float* __restrict__ W2, const float* __restrict__ W3,
    unsigned short* __restrict__ T0, unsigned short* __restrict__ T1,
    unsigned short* __restrict__ T2, unsigned short* __restrict__ T3) {
    const int bx = blockIdx.x;
    if (bx < 1024) {
        const int z = bx >> 8, rem = bx & 255;
        const float* W = (z == 0) ? W0 : (z == 1) ? W1 : (z == 2) ? W2 : W3;
        unsigned short* T = (z == 0) ? T0 : (z == 1) ? T1 : (z == 2) ? T2 : T3;
        __shared__ float t[64][65];
        const int bn = (rem & 15) * 64, bk = (rem >> 4) * 64;
        const int tx = threadIdx.x & 63, ty = threadIdx.x >> 6;  // ty 0..3
        #pragma unroll
        for (int m = 0; m < 16; ++m)            // 64 k-rows, 256B reads
            t[ty + m * 4][tx] = W[(size_t)(bk + ty + m * 4) * 1024 + bn + tx];
        __syncthreads();
        #pragma unroll
        for (int m = 0; m < 16; ++m)            // 64 n-rows, 128B writes
            T[(size_t)(bn + ty + m * 4) * 1024 + bk + tx] =
                f2bf(t[tx][ty + m * 4]);
    } else {
        const int i = (bx - 1024) * 2048 + threadIdx.x * 8;
        float4 f0 = *(const float4*)(x + i);
        float4 f1 = *(const float4*)(x + i + 4);
        ushort4 o0, o1;
        o0.x = f2bf(f0.x); o0.y = f2bf(f0.y); o0.z = f2bf(f0.z); o0.w = f2bf(f0.w);
        o1.x = f2bf(f1.x); o1.y = f2bf(f1.y); o1.z = f2bf(f1.z); o1.w = f2bf(f1.w);
        *(ushort4*)(xb + i) = o0;
        *(ushort4*)(xb + i + 4) = o1;
    }
}

// ---------------------------------------------------------------------------
// QKV GEMM (r26): 64x128 tile, BK=32, grid (24,32) = 768 blocks (3/CU),
// GLL width-16 staging, 3-buffer counted-vmcnt pipeline. Fused RoPE
// epilogue, head-major bf16 out [H][S][64].
// ---------------------------------------------------------------------------
__global__ __launch_bounds__(256) void gemm_qkv(
    const unsigned short* __restrict__ xb,
    const unsigned short* __restrict__ Wtq, const unsigned short* __restrict__ Wtk,
    const unsigned short* __restrict__ Wtv,
    unsigned short* __restrict__ qh, unsigned short* __restrict__ kh,
    unsigned short* __restrict__ vh,
    const float* __restrict__ cs, const float* __restrict__ sn) {
    __shared__ __align__(16) unsigned short Al[3][64 * 32];
    __shared__ __align__(16) unsigned short Bl[3][128 * 32];
    const int tid = threadIdx.x;
    const int nb = blockIdx.x >> 3;
    const unsigned short* __restrict__ Bt = (nb == 0) ? Wtq : (nb == 1) ? Wtk : Wtv;
    unsigned short* __restrict__ OUT = (nb == 0) ? qh : (nb == 1) ? kh : vh;
    const int col0 = (blockIdx.x & 7) * 128;
    const int row0 = blockIdx.y * 64;
    const int lane = tid & 63, wvi = tid >> 6;
    const int wr = (wvi >> 1) * 32, wc = (wvi & 1) * 64;
    const int l15 = lane & 15, quad = lane >> 4;

    const int grow = lane >> 2;            // 0..15
    const int gkc = (lane & 3) * 8;        // element offset within row
    const unsigned short* gA = xb + (size_t)(row0 + wvi * 16 + grow) * 1024 + gkc;
    const unsigned short* gB = Bt + (size_t)(col0 + wvi * 32 + grow) * 1024 + gkc;
    const int lAo = (wvi * 16) * 32;       // wave-uniform offsets in a buffer
    const int lBo = (wvi * 32) * 32;

    f32x4 acc[2][4] = {};
    // prologue: stage tiles 0,1 into bufs 0,1
    gll16(gA, Al[0] + lAo);
    gll16(gB, Bl[0] + lBo);
    gll16(gB + 16 * 1024, Bl[0] + lBo + 16 * 32);
    gll16(gA + 32, Al[1] + lAo);
    gll16(gB + 32, Bl[1] + lBo);
    gll16(gB + 16 * 1024 + 32, Bl[1] + lBo + 16 * 32);
    asm volatile("s_waitcnt vmcnt(3)" ::: "memory");   // tile 0 landed
    __builtin_amdgcn_s_barrier();
    int cur = 0;
    for (int it = 0; it < 32; ++it) {
        bf16x8 af[2], bfr[4];
        #pragma unroll
        for (int i = 0; i < 2; ++i)
            af[i] = *(const bf16x8*)&Al[cur][(wr + i * 16 + l15) * 32 + quad * 8];
        #pragma unroll
        for (int j = 0; j < 4; ++j)
            bfr[j] = *(const bf16x8*)&Bl[cur][(wc + j * 16 + l15) * 32 + quad * 8];
        if (it < 30) {                      // stage tile it+2 into buf cur+2
            const int k2 = (it + 2) * 32;
            const int st = (cur + 2 >= 3) ? cur - 1 : cur + 2;
            gll16(gA + k2, Al[st] + lAo);
            gll16(gB + k2, Bl[st] + lBo);
            gll16(gB + 16 * 1024 + k2, Bl[st] + lBo + 16 * 32);
        }
        #pragma unroll
        for (int i = 0; i < 2; ++i)
            #pragma unroll
            for (int j = 0; j < 4; ++j)
                acc[i][j] = __builtin_amdgcn_mfma_f32_16x16x32_bf16(
                    af[i], bfr[j], acc[i][j], 0, 0, 0);
        if (it < 30)
            asm volatile("s_waitcnt vmcnt(3)" ::: "memory");  // tile it+1 landed
        else
            asm volatile("s_waitcnt vmcnt(0)" ::: "memory");
        __builtin_amdgcn_s_barrier();
        cur = (cur >= 2) ? 0 : cur + 1;
    }

    // epilogue: wave's 64 cols = one head; fused RoPE; head-major store
    const int hh = ((blockIdx.x & 7) << 1) + (wc >> 6);
    const bool dorope = (nb != 2);
    #pragma unroll
    for (int i = 0; i < 2; ++i) {
        const int rowb = row0 + wr + i * 16 + quad * 4;
        #pragma unroll
        for (int r = 0; r < 4; ++r) {
            const int s = rowb + r;
            float v0 = acc[i][0][r], v1 = acc[i][1][r];
            float v2 = acc[i][2][r], v3 = acc[i][3][r];
            if (dorope) {
                float c0 = cs[s * 32 + l15],      s0 = sn[s * 32 + l15];
                float c1 = cs[s * 32 + 16 + l15], s1 = sn[s * 32 + 16 + l15];
                float lo0 = v0 * c0 - v2 * s0;
                float hi0 = v2 * c0 + v0 * s0;
                float lo1 = v1 * c1 - v3 * s1;
                float hi1 = v3 * c1 + v1 * s1;
                v0 = lo0; v1 = lo1; v2 = hi0; v3 = hi1;
            }
            unsigned short* op = OUT + (size_t)hh * (S_LEN * 64) + (size_t)s * 64 + l15;
            op[0]  = f2bf(v0);
            op[16] = f2bf(v1);
            op[32] = f2bf(v2);
            op[48] = f2bf(v3);
        }
    }
}

// ---------------------------------------------------------------------------
// Attention (r21-verbatim, FROZEN): one wave per (h,q); XCD-aware head
// remap; wave-private LDS slices; same-address broadcast ds_reads;
// phase-4 vectorized V gather (uint2 x16) with addresses from ts.
// ---------------------------------------------------------------------------
__global__ __launch_bounds__(256) void attn_kernel(
    const unsigned short* __restrict__ qh, const unsigned short* __restrict__ kh,
    const unsigned short* __restrict__ vh, const int* __restrict__ anc,
    unsigned short* __restrict__ att) {
    __shared__ __align__(16) float qs[4][64];
    __shared__ __align__(16) int   ts[4][64];
    __shared__ __align__(16) float ws[4][64];
    const int w4 = threadIdx.x >> 6;
    const int lane = threadIdx.x & 63;
    // XCD-aware remap (bijective over 8192 blocks): each XCD owns 2 heads.
    const int bid = blockIdx.x;
    const int xcd = bid & 7;
    const int idx = bid >> 3;                  // 0..1023
    const int h   = (xcd << 1) | (idx >> 9);   // 2 heads per XCD
    const int qi  = ((idx & 511) << 2) + w4;   // 512 q-blocks per head
    const size_t hb = (size_t)h * (S_LEN * 64);

    const float q_own = bfu2f(qh[hb + (size_t)qi * 64 + lane]);
    const int slot = lane >> 4;
    const int tile = (slot < 3) ? anc[((size_t)h * S_LEN + qi) * 3 + slot]
                                : (qi >> 4);
    const int tok_own = tile * 16 + (lane & 15);
    qs[w4][lane] = q_own;
    ts[w4][lane] = tok_own;

    const int c = lane & 3;
    const int t = lane >> 2;
    float qv[16];
    #pragma unroll
    for (int r = 0; r < 4; ++r) {
        float4 f = *(const float4*)&qs[w4][c * 16 + r * 4];
        qv[r * 4 + 0] = f.x; qv[r * 4 + 1] = f.y;
        qv[r * 4 + 2] = f.z; qv[r * 4 + 3] = f.w;
    }

    #pragma unroll
    for (int p = 0; p < 4; ++p) {
        const int tk = ts[w4][p * 16 + t];
        const unsigned short* kp = kh + hb + (size_t)tk * 64 + c * 16;
        const uint4 k0 = *(const uint4*)kp;
        const uint4 k1 = *(const uint4*)(kp + 8);
        float part;
        part = bflo(k0.x) * qv[0];
        part = fmaf(bfhi(k0.x), qv[1], part);
        part = fmaf(bflo(k0.y), qv[2], part);
        part = fmaf(bfhi(k0.y), qv[3], part);
        part = fmaf(bflo(k0.z), qv[4], part);
        part = fmaf(bfhi(k0.z), qv[5], part);
        part = fmaf(bflo(k0.w), qv[6], part);
        part = fmaf(bfhi(k0.w), qv[7], part);
        part = fmaf(bflo(k1.x), qv[8], part);
        part = fmaf(bfhi(k1.x), qv[9], part);
        part = fmaf(bflo(k1.y), qv[10], part);
        part = fmaf(bfhi(k1.y), qv[11], part);
        part = fmaf(bflo(k1.z), qv[12], part);
        part = fmaf(bfhi(k1.z), qv[13], part);
        part = fmaf(bflo(k1.w), qv[14], part);
        part = fmaf(bfhi(k1.w), qv[15], part);
        part += __shfl_xor(part, 1, 64);
        part += __shfl_xor(part, 2, 64);
        if (c == 0) ws[w4][p * 16 + t] = part;
    }

    float logit = ws[w4][lane];
    const bool fut = tok_own > qi;
    logit = fut ? -1e30f : logit * 0.125f;

    float m = logit;
    #pragma unroll
    for (int off = 32; off >= 1; off >>= 1)
        m = fmaxf(m, __shfl_xor(m, off, 64));
    const float e = fut ? 0.f : __expf(logit - m);
    float ssum = e;
    #pragma unroll
    for (int off = 32; off >= 1; off >>= 1)
        ssum += __shfl_xor(ssum, off, 64);
    ws[w4][lane] = e / ssum;

    // phase 4: vectorized weighted V sum.
    // lane -> (tq = token quad 0..3, dd = dim quad 0..15); round r covers
    // tokens r*4 .. r*4+3; each lane loads 4 bf16 dims (uint2, 8B).
    const int tq = lane >> 4;
    const int dd = lane & 15;
    const unsigned short* vbase = vh + hb + dd * 4;
    float a0 = 0.f, a1 = 0.f, a2 = 0.f, a3 = 0.f;
    #pragma unroll
    for (int r = 0; r < 16; ++r) {
        const int kk = r * 4 + tq;
        const int tok = ts[w4][kk];
        const uint2 vv = *(const uint2*)(vbase + (size_t)tok * 64);
        const float w = ws[w4][kk];
        a0 = fmaf(w, bflo(vv.x), a0);
        a1 = fmaf(w, bfhi(vv.x), a1);
        a2 = fmaf(w, bflo(vv.y), a2);
        a3 = fmaf(w, bfhi(vv.y), a3);
    }
    a0 += __shfl_xor(a0, 16, 64); a0 += __shfl_xor(a0, 32, 64);
    a1 += __shfl_xor(a1, 16, 64); a1 += __shfl_xor(a1, 32, 64);
    a2 += __shfl_xor(a2, 16, 64); a2 += __shfl_xor(a2, 32, 64);
    a3 += __shfl_xor(a3, 16, 64); a3 += __shfl_xor(a3, 32, 64);
    if (tq == 0) {
        ushort4 o;
        o.x = f2bf(a0); o.y = f2bf(a1); o.z = f2bf(a2); o.w = f2bf(a3);
        *(ushort4*)&att[(size_t)qi * DM + h * HD + dd * 4] = o;
    }
}

// ---------------------------------------------------------------------------
// Out GEMM (r26): 64x64 tile, grid (16,32) = 512 blocks = 2/CU, 3-buffer
// counted-vmcnt pipeline (vmcnt(2): 2 GLL per tile). Wave tile 32x32.
// ---------------------------------------------------------------------------
__global__ __launch_bounds__(256) void gemm_out(
    const unsigned short* __restrict__ A, const unsigned short* __restrict__ Bt,
    float* __restrict__ C) {
    __shared__ __align__(16) unsigned short Al[3][64 * 32];
    __shared__ __align__(16) unsigned short Bl[3][64 * 32];
    const int tid = threadIdx.x;
    const int col0 = blockIdx.x * 64;
    const int row0 = blockIdx.y * 64;
    const int lane = tid & 63, wvi = tid >> 6;
    const int wr = (wvi >> 1) * 32, wc = (wvi & 1) * 32;
    const int l15 = lane & 15, quad = lane >> 4;

    const int grow = lane >> 2;
    const int gkc = (lane & 3) * 8;
    const unsigned short* gA = A + (size_t)(row0 + wvi * 16 + grow) * 1024 + gkc;
    const unsigned short* gB = Bt + (size_t)(col0 + wvi * 16 + grow) * 1024 + gkc;
    const int lAo = (wvi * 16) * 32;       // wave-uniform offsets in a buffer
    const int lBo = (wvi * 16) * 32;

    f32x4 acc[2][2] = {};
    // prologue: stage tiles 0,1 into bufs 0,1
    gll16(gA, Al[0] + lAo);
    gll16(gB, Bl[0] + lBo);
    gll16(gA + 32, Al[1] + lAo);
    gll16(gB + 32, Bl[1] + lBo);
    asm volatile("s_waitcnt vmcnt(2)" ::: "memory");   // tile 0 landed
    __builtin_amdgcn_s_barrier();
    int cur = 0;
    for (int it = 0; it < 32; ++it) {
        bf16x8 af[2], bfr[2];
        #pragma unroll
        for (int i = 0; i < 2; ++i)
            af[i] = *(const bf16x8*)&Al[cur][(wr + i * 16 + l15) * 32 + quad * 8];
        #pragma unroll
        for (int j = 0; j < 2; ++j)
            bfr[j] = *(const bf16x8*)&Bl[cur][(wc + j * 16 + l15) * 32 + quad * 8];
        if (it < 30) {                      // stage tile it+2
            const int k2 = (it + 2) * 32;
            const int st = (cur + 2 >= 3) ? cur - 1 : cur + 2;
            gll16(gA + k2, Al[st] + lAo);
            gll16(gB + k2, Bl[st] + lBo);
        }
        #pragma unroll
        for (int i = 0; i < 2; ++i)
            #pragma unroll
            for (int j = 0; j < 2; ++j)
                acc[i][j] = __builtin_amdgcn_mfma_f32_16x16x32_bf16(
                    af[i], bfr[j], acc[i][j], 0, 0, 0);
        if (it < 30)
            asm volatile("s_waitcnt vmcnt(2)" ::: "memory");  // tile it+1 landed
        else
            asm volatile("s_waitcnt vmcnt(0)" ::: "memory");
        __builtin_amdgcn_s_barrier();
        cur = (cur >= 2) ? 0 : cur + 1;
    }
    #pragma unroll
    for (int i = 0; i < 2; ++i) {
        const int rowb = row0 + wr + i * 16 + quad * 4;
        #pragma unroll
        for (int r = 0; r < 4; ++r) {
            float* crow = C + (size_t)(rowb + r) * 1024 + col0 + wc;
            #pragma unroll
            for (int j = 0; j < 2; ++j)
                crow[j * 16 + l15] = acc[i][j][r];
        }
    }
}

// ---------------------------------------------------------------------------
extern "C" void kernel_launch(void* const* d_in, const int* in_sizes, int n_in,
                              void* d_out, int out_size, void* d_ws, size_t ws_size,
                              hipStream_t stream) {
    const float* x   = (const float*)d_in[0];
    const float* Wq  = (const float*)d_in[1];
    const float* Wk  = (const float*)d_in[2];
    const float* Wv  = (const float*)d_in[3];
    const float* Wo  = (const float*)d_in[4];
    const float* cs  = (const float*)d_in[5];
    const float* sn  = (const float*)d_in[6];
    const int*   anc = (const int*)d_in[7];
    float* out = (float*)d_out;

    unsigned short* xb  = (unsigned short*)d_ws;
    unsigned short* Wtq = xb  + (size_t)2048 * 1024;
    unsigned short* Wtk = Wtq + (size_t)1024 * 1024;
    unsigned short* Wtv = Wtk + (size_t)1024 * 1024;
    unsigned short* Wto = Wtv + (size_t)1024 * 1024;
    unsigned short* qh  = Wto + (size_t)1024 * 1024;   // [H][S][64]
    unsigned short* kh  = qh  + (size_t)2048 * 1024;
    unsigned short* vh  = kh  + (size_t)2048 * 1024;
    unsigned short* att = vh  + (size_t)2048 * 1024;   // [S][H*D]

    prep<<<2048, 256, 0, stream>>>(x, xb, Wq, Wk, Wv, Wo, Wtq, Wtk, Wtv, Wto);
    gemm_qkv<<<dim3(24, 32), 256, 0, stream>>>(xb, Wtq, Wtk, Wtv,
                                               qh, kh, vh, cs, sn);
    attn_kernel<<<(S_LEN * NH) / 4, 256, 0, stream>>>(qh, kh, vh, anc, att);
    gemm_out<<<dim3(16, 32), 256, 0, stream>>>(att, Wto, out);
}

// Round 11
// 144.725 us; speedup vs baseline: 1.3121x; 1.0045x over previous
//
#include <hip/hip_runtime.h>
#include <hip/hip_bf16.h>

// KascadeReuseAttention  B=1, S=2048, DM=1024, H=16, D=64, T=16, NA=3
// Round-27 (base r26 = 145.4us): single change — both GEMMs move to
// BK=64 (was 32), 2-buffer stage-ahead, ONE barrier per K-iter (16
// iters). Rationale: r26's counted-vmcnt gave only -1.1us because the
// per-iter compute window (~300cyc: 8 MFMA + 6 ds_read) couldn't cover
// the 500-900cyc load flight; BK=64 doubles the window (16 MFMA + 12
// ds_read) and halves barrier count. LDS: qkv 48KB (3 blocks/CU kept —
// m132's BK=128 regression was occupancy loss, avoided here), out 32KB
// (2/CU kept). ks=0,1 subtile loop preserves exact BK=32 accumulation
// order -> bit-identical. attn frozen (r21); prep frozen (r25).
// History: r18/r22 attn regressions (VGPR-40 collapse; DPP banned),
// r20 qkv dbuf +1.3, r21 XCD remap ~0, r25 prep retile + out dbuf -3.5,
// r26 counted-vmcnt -1.1.
// Budget: ~45us ws-poison fill (immovable) + ~35 attn + qkv + prep +
// out + gaps.

#define S_LEN 2048
#define DM 1024
#define NH 16
#define HD 64

typedef __bf16 bf16x8 __attribute__((ext_vector_type(8)));
typedef float f32x4 __attribute__((ext_vector_type(4)));

static __device__ __forceinline__ unsigned short f2bf(float f) {
    union { float f; unsigned int i; } un;
    un.f = f;
    unsigned int r = un.i + 0x7FFFu + ((un.i >> 16) & 1u);  // RNE
    return (unsigned short)(r >> 16);
}
static __device__ __forceinline__ float bfu2f(unsigned short u) {
    union { unsigned int i; float f; } un;
    un.i = ((unsigned int)u) << 16;
    return un.f;
}
static __device__ __forceinline__ float bflo(unsigned int u) {
    union { unsigned int i; float f; } un;
    un.i = u << 16;
    return un.f;
}
static __device__ __forceinline__ float bfhi(unsigned int u) {
    union { unsigned int i; float f; } un;
    un.i = u & 0xFFFF0000u;
    return un.f;
}

// async global->LDS, 16 B per lane; LDS dest = uniform base + lane*16.
static __device__ __forceinline__ void gll16(const unsigned short* g,
                                             unsigned short* l) {
    __builtin_amdgcn_global_load_lds(
        (const __attribute__((address_space(1))) unsigned int*)(uintptr_t)g,
        (__attribute__((address_space(3))) unsigned int*)(uintptr_t)l,
        16, 0, 0);
}

// ---------------------------------------------------------------------------
// prep (r25-verbatim): blocks [0,1024) transpose W* fp32->bf16 [n][k] in
// 64x64 tiles (LDS [64][65]); blocks [1024,2048) convert x fp32->bf16.
// ---------------------------------------------------------------------------
__global__ __launch_bounds__(256) void prep(
    const float* __restrict__ x, unsigned short* __restrict__ xb,
    const float* __restrict__ W0, const float* __restrict__ W1,
    const float* __restrict__ W2, const float* __restrict__ W3,
    unsigned short* __restrict__ T0, unsigned short* __restrict__ T1,
    unsigned short* __restrict__ T2, unsigned short* __restrict__ T3) {
    const int bx = blockIdx.x;
    if (bx < 1024) {
        const int z = bx >> 8, rem = bx & 255;
        const float* W = (z == 0) ? W0 : (z == 1) ? W1 : (z == 2) ? W2 : W3;
        unsigned short* T = (z == 0) ? T0 : (z == 1) ? T1 : (z == 2) ? T2 : T3;
        __shared__ float t[64][65];
        const int bn = (rem & 15) * 64, bk = (rem >> 4) * 64;
        const int tx = threadIdx.x & 63, ty = threadIdx.x >> 6;  // ty 0..3
        #pragma unroll
        for (int m = 0; m < 16; ++m)            // 64 k-rows, 256B reads
            t[ty + m * 4][tx] = W[(size_t)(bk + ty + m * 4) * 1024 + bn + tx];
        __syncthreads();
        #pragma unroll
        for (int m = 0; m < 16; ++m)            // 64 n-rows, 128B writes
            T[(size_t)(bn + ty + m * 4) * 1024 + bk + tx] =
                f2bf(t[tx][ty + m * 4]);
    } else {
        const int i = (bx - 1024) * 2048 + threadIdx.x * 8;
        float4 f0 = *(const float4*)(x + i);
        float4 f1 = *(const float4*)(x + i + 4);
        ushort4 o0, o1;
        o0.x = f2bf(f0.x); o0.y = f2bf(f0.y); o0.z = f2bf(f0.z); o0.w = f2bf(f0.w);
        o1.x = f2bf(f1.x); o1.y = f2bf(f1.y); o1.z = f2bf(f1.z); o1.w = f2bf(f1.w);
        *(ushort4*)(xb + i) = o0;
        *(ushort4*)(xb + i + 4) = o1;
    }
}

// ---------------------------------------------------------------------------
// QKV GEMM (r27): 64x128 tile, BK=64, grid (24,32) = 768 blocks (3/CU),
// GLL width-16 staging (6 calls/thread/iter), 2-buffer stage-ahead, one
// barrier per iter (16 iters). Fused RoPE epilogue, head-major out.
// LDS layout per buffer: A[64][64], B[128][64] bf16.
// ---------------------------------------------------------------------------
__global__ __launch_bounds__(256) void gemm_qkv(
    const unsigned short* __restrict__ xb,
    const unsigned short* __restrict__ Wtq, const unsigned short* __restrict__ Wtk,
    const unsigned short* __restrict__ Wtv,
    unsigned short* __restrict__ qh, unsigned short* __restrict__ kh,
    unsigned short* __restrict__ vh,
    const float* __restrict__ cs, const float* __restrict__ sn) {
    __shared__ __align__(16) unsigned short Al[2][64 * 64];
    __shared__ __align__(16) unsigned short Bl[2][128 * 64];
    const int tid = threadIdx.x;
    const int nb = blockIdx.x >> 3;
    const unsigned short* __restrict__ Bt = (nb == 0) ? Wtq : (nb == 1) ? Wtk : Wtv;
    unsigned short* __restrict__ OUT = (nb == 0) ? qh : (nb == 1) ? kh : vh;
    const int col0 = (blockIdx.x & 7) * 128;
    const int row0 = blockIdx.y * 64;
    const int lane = tid & 63, wvi = tid >> 6;
    const int wr = (wvi >> 1) * 32, wc = (wvi & 1) * 64;
    const int l15 = lane & 15, quad = lane >> 4;

    // BK=64 staging: 8 lanes per 128B row, 8 rows per gll16 call.
    const int grow8 = lane >> 3;           // 0..7
    const int gkc8 = (lane & 7) * 8;       // element offset within row
    const unsigned short* gA = xb + (size_t)(row0 + wvi * 16 + grow8) * 1024 + gkc8;
    const unsigned short* gB = Bt + (size_t)(col0 + wvi * 32 + grow8) * 1024 + gkc8;
    const int lAo = (wvi * 16) * 64;       // wave-uniform offsets in a buffer
    const int lBo = (wvi * 32) * 64;

    f32x4 acc[2][4] = {};
    // prologue: stage tile 0 into buf 0 (A: 2 calls, B: 4 calls per wave)
    gll16(gA, Al[0] + lAo);
    gll16(gA + 8 * 1024, Al[0] + lAo + 8 * 64);
    gll16(gB, Bl[0] + lBo);
    gll16(gB + 8 * 1024, Bl[0] + lBo + 8 * 64);
    gll16(gB + 16 * 1024, Bl[0] + lBo + 16 * 64);
    gll16(gB + 24 * 1024, Bl[0] + lBo + 24 * 64);
    __syncthreads();
    for (int it = 0; it < 16; ++it) {
        const int cur = it & 1;
        if (it < 15) {                      // issue next-tile loads first
            const int k1 = (it + 1) * 64;
            const int nx = cur ^ 1;
            gll16(gA + k1, Al[nx] + lAo);
            gll16(gA + 8 * 1024 + k1, Al[nx] + lAo + 8 * 64);
            gll16(gB + k1, Bl[nx] + lBo);
            gll16(gB + 8 * 1024 + k1, Bl[nx] + lBo + 8 * 64);
            gll16(gB + 16 * 1024 + k1, Bl[nx] + lBo + 16 * 64);
            gll16(gB + 24 * 1024 + k1, Bl[nx] + lBo + 24 * 64);
        }
        #pragma unroll
        for (int ks = 0; ks < 2; ++ks) {
            bf16x8 af[2], bfr[4];
            #pragma unroll
            for (int i = 0; i < 2; ++i)
                af[i] = *(const bf16x8*)
                    &Al[cur][(wr + i * 16 + l15) * 64 + ks * 32 + quad * 8];
            #pragma unroll
            for (int j = 0; j < 4; ++j)
                bfr[j] = *(const bf16x8*)
                    &Bl[cur][(wc + j * 16 + l15) * 64 + ks * 32 + quad * 8];
            #pragma unroll
            for (int i = 0; i < 2; ++i)
                #pragma unroll
                for (int j = 0; j < 4; ++j)
                    acc[i][j] = __builtin_amdgcn_mfma_f32_16x16x32_bf16(
                        af[i], bfr[j], acc[i][j], 0, 0, 0);
        }
        __syncthreads();   // drains next-tile GLLs (flew under 2x compute)
    }

    // epilogue: wave's 64 cols = one head; fused RoPE; head-major store
    const int hh = ((blockIdx.x & 7) << 1) + (wc >> 6);
    const bool dorope = (nb != 2);
    #pragma unroll
    for (int i = 0; i < 2; ++i) {
        const int rowb = row0 + wr + i * 16 + quad * 4;
        #pragma unroll
        for (int r = 0; r < 4; ++r) {
            const int s = rowb + r;
            float v0 = acc[i][0][r], v1 = acc[i][1][r];
            float v2 = acc[i][2][r], v3 = acc[i][3][r];
            if (dorope) {
                float c0 = cs[s * 32 + l15],      s0 = sn[s * 32 + l15];
                float c1 = cs[s * 32 + 16 + l15], s1 = sn[s * 32 + 16 + l15];
                float lo0 = v0 * c0 - v2 * s0;
                float hi0 = v2 * c0 + v0 * s0;
                float lo1 = v1 * c1 - v3 * s1;
                float hi1 = v3 * c1 + v1 * s1;
                v0 = lo0; v1 = lo1; v2 = hi0; v3 = hi1;
            }
            unsigned short* op = OUT + (size_t)hh * (S_LEN * 64) + (size_t)s * 64 + l15;
            op[0]  = f2bf(v0);
            op[16] = f2bf(v1);
            op[32] = f2bf(v2);
            op[48] = f2bf(v3);
        }
    }
}

// ---------------------------------------------------------------------------
// Attention (r21-verbatim, FROZEN): one wave per (h,q); XCD-aware head
// remap; wave-private LDS slices; same-address broadcast ds_reads;
// phase-4 vectorized V gather (uint2 x16) with addresses from ts.
// ---------------------------------------------------------------------------
__global__ __launch_bounds__(256) void attn_kernel(
    const unsigned short* __restrict__ qh, const unsigned short* __restrict__ kh,
    const unsigned short* __restrict__ vh, const int* __restrict__ anc,
    unsigned short* __restrict__ att) {
    __shared__ __align__(16) float qs[4][64];
    __shared__ __align__(16) int   ts[4][64];
    __shared__ __align__(16) float ws[4][64];
    const int w4 = threadIdx.x >> 6;
    const int lane = threadIdx.x & 63;
    // XCD-aware remap (bijective over 8192 blocks): each XCD owns 2 heads.
    const int bid = blockIdx.x;
    const int xcd = bid & 7;
    const int idx = bid >> 3;                  // 0..1023
    const int h   = (xcd << 1) | (idx >> 9);   // 2 heads per XCD
    const int qi  = ((idx & 511) << 2) + w4;   // 512 q-blocks per head
    const size_t hb = (size_t)h * (S_LEN * 64);

    const float q_own = bfu2f(qh[hb + (size_t)qi * 64 + lane]);
    const int slot = lane >> 4;
    const int tile = (slot < 3) ? anc[((size_t)h * S_LEN + qi) * 3 + slot]
                                : (qi >> 4);
    const int tok_own = tile * 16 + (lane & 15);
    qs[w4][lane] = q_own;
    ts[w4][lane] = tok_own;

    const int c = lane & 3;
    const int t = lane >> 2;
    float qv[16];
    #pragma unroll
    for (int r = 0; r < 4; ++r) {
        float4 f = *(const float4*)&qs[w4][c * 16 + r * 4];
        qv[r * 4 + 0] = f.x; qv[r * 4 + 1] = f.y;
        qv[r * 4 + 2] = f.z; qv[r * 4 + 3] = f.w;
    }

    #pragma unroll
    for (int p = 0; p < 4; ++p) {
        const int tk = ts[w4][p * 16 + t];
        const unsigned short* kp = kh + hb + (size_t)tk * 64 + c * 16;
        const uint4 k0 = *(const uint4*)kp;
        const uint4 k1 = *(const uint4*)(kp + 8);
        float part;
        part = bflo(k0.x) * qv[0];
        part = fmaf(bfhi(k0.x), qv[1], part);
        part = fmaf(bflo(k0.y), qv[2], part);
        part = fmaf(bfhi(k0.y), qv[3], part);
        part = fmaf(bflo(k0.z), qv[4], part);
        part = fmaf(bfhi(k0.z), qv[5], part);
        part = fmaf(bflo(k0.w), qv[6], part);
        part = fmaf(bfhi(k0.w), qv[7], part);
        part = fmaf(bflo(k1.x), qv[8], part);
        part = fmaf(bfhi(k1.x), qv[9], part);
        part = fmaf(bflo(k1.y), qv[10], part);
        part = fmaf(bfhi(k1.y), qv[11], part);
        part = fmaf(bflo(k1.z), qv[12], part);
        part = fmaf(bfhi(k1.z), qv[13], part);
        part = fmaf(bflo(k1.w), qv[14], part);
        part = fmaf(bfhi(k1.w), qv[15], part);
        part += __shfl_xor(part, 1, 64);
        part += __shfl_xor(part, 2, 64);
        if (c == 0) ws[w4][p * 16 + t] = part;
    }

    float logit = ws[w4][lane];
    const bool fut = tok_own > qi;
    logit = fut ? -1e30f : logit * 0.125f;

    float m = logit;
    #pragma unroll
    for (int off = 32; off >= 1; off >>= 1)
        m = fmaxf(m, __shfl_xor(m, off, 64));
    const float e = fut ? 0.f : __expf(logit - m);
    float ssum = e;
    #pragma unroll
    for (int off = 32; off >= 1; off >>= 1)
        ssum += __shfl_xor(ssum, off, 64);
    ws[w4][lane] = e / ssum;

    // phase 4: vectorized weighted V sum.
    // lane -> (tq = token quad 0..3, dd = dim quad 0..15); round r covers
    // tokens r*4 .. r*4+3; each lane loads 4 bf16 dims (uint2, 8B).
    const int tq = lane >> 4;
    const int dd = lane & 15;
    const unsigned short* vbase = vh + hb + dd * 4;
    float a0 = 0.f, a1 = 0.f, a2 = 0.f, a3 = 0.f;
    #pragma unroll
    for (int r = 0; r < 16; ++r) {
        const int kk = r * 4 + tq;
        const int tok = ts[w4][kk];
        const uint2 vv = *(const uint2*)(vbase + (size_t)tok * 64);
        const float w = ws[w4][kk];
        a0 = fmaf(w, bflo(vv.x), a0);
        a1 = fmaf(w, bfhi(vv.x), a1);
        a2 = fmaf(w, bflo(vv.y), a2);
        a3 = fmaf(w, bfhi(vv.y), a3);
    }
    a0 += __shfl_xor(a0, 16, 64); a0 += __shfl_xor(a0, 32, 64);
    a1 += __shfl_xor(a1, 16, 64); a1 += __shfl_xor(a1, 32, 64);
    a2 += __shfl_xor(a2, 16, 64); a2 += __shfl_xor(a2, 32, 64);
    a3 += __shfl_xor(a3, 16, 64); a3 += __shfl_xor(a3, 32, 64);
    if (tq == 0) {
        ushort4 o;
        o.x = f2bf(a0); o.y = f2bf(a1); o.z = f2bf(a2); o.w = f2bf(a3);
        *(ushort4*)&att[(size_t)qi * DM + h * HD + dd * 4] = o;
    }
}

// ---------------------------------------------------------------------------
// Out GEMM (r27): 64x64 tile, BK=64, grid (16,32) = 512 blocks = 2/CU,
// 2-buffer stage-ahead, one barrier per iter (16 iters). Wave tile 32x32.
// LDS per buffer: A[64][64], B[64][64] bf16 (32KB total).
// ---------------------------------------------------------------------------
__global__ __launch_bounds__(256) void gemm_out(
    const unsigned short* __restrict__ A, const unsigned short* __restrict__ Bt,
    float* __restrict__ C) {
    __shared__ __align__(16) unsigned short Al[2][64 * 64];
    __shared__ __align__(16) unsigned short Bl[2][64 * 64];
    const int tid = threadIdx.x;
    const int col0 = blockIdx.x * 64;
    const int row0 = blockIdx.y * 64;
    const int lane = tid & 63, wvi = tid >> 6;
    const int wr = (wvi >> 1) * 32, wc = (wvi & 1) * 32;
    const int l15 = lane & 15, quad = lane >> 4;

    const int grow8 = lane >> 3;
    const int gkc8 = (lane & 7) * 8;
    const unsigned short* gA = A + (size_t)(row0 + wvi * 16 + grow8) * 1024 + gkc8;
    const unsigned short* gB = Bt + (size_t)(col0 + wvi * 16 + grow8) * 1024 + gkc8;
    const int lAo = (wvi * 16) * 64;       // wave-uniform offsets in a buffer
    const int lBo = (wvi * 16) * 64;

    f32x4 acc[2][2] = {};
    // prologue: stage tile 0 into buf 0 (2 calls each for A and B)
    gll16(gA, Al[0] + lAo);
    gll16(gA + 8 * 1024, Al[0] + lAo + 8 * 64);
    gll16(gB, Bl[0] + lBo);
    gll16(gB + 8 * 1024, Bl[0] + lBo + 8 * 64);
    __syncthreads();
    for (int it = 0; it < 16; ++it) {
        const int cur = it & 1;
        if (it < 15) {                      // issue next-tile loads first
            const int k1 = (it + 1) * 64;
            const int nx = cur ^ 1;
            gll16(gA + k1, Al[nx] + lAo);
            gll16(gA + 8 * 1024 + k1, Al[nx] + lAo + 8 * 64);
            gll16(gB + k1, Bl[nx] + lBo);
            gll16(gB + 8 * 1024 + k1, Bl[nx] + lBo + 8 * 64);
        }
        #pragma unroll
        for (int ks = 0; ks < 2; ++ks) {
            bf16x8 af[2], bfr[2];
            #pragma unroll
            for (int i = 0; i < 2; ++i)
                af[i] = *(const bf16x8*)
                    &Al[cur][(wr + i * 16 + l15) * 64 + ks * 32 + quad * 8];
            #pragma unroll
            for (int j = 0; j < 2; ++j)
                bfr[j] = *(const bf16x8*)
                    &Bl[cur][(wc + j * 16 + l15) * 64 + ks * 32 + quad * 8];
            #pragma unroll
            for (int i = 0; i < 2; ++i)
                #pragma unroll
                for (int j = 0; j < 2; ++j)
                    acc[i][j] = __builtin_amdgcn_mfma_f32_16x16x32_bf16(
                        af[i], bfr[j], acc[i][j], 0, 0, 0);
        }
        __syncthreads();
    }
    #pragma unroll
    for (int i = 0; i < 2; ++i) {
        const int rowb = row0 + wr + i * 16 + quad * 4;
        #pragma unroll
        for (int r = 0; r < 4; ++r) {
            float* crow = C + (size_t)(rowb + r) * 1024 + col0 + wc;
            #pragma unroll
            for (int j = 0; j < 2; ++j)
                crow[j * 16 + l15] = acc[i][j][r];
        }
    }
}

// ---------------------------------------------------------------------------
extern "C" void kernel_launch(void* const* d_in, const int* in_sizes, int n_in,
                              void* d_out, int out_size, void* d_ws, size_t ws_size,
                              hipStream_t stream) {
    const float* x   = (const float*)d_in[0];
    const float* Wq  = (const float*)d_in[1];
    const float* Wk  = (const float*)d_in[2];
    const float* Wv  = (const float*)d_in[3];
    const float* Wo  = (const float*)d_in[4];
    const float* cs  = (const float*)d_in[5];
    const float* sn  = (const float*)d_in[6];
    const int*   anc = (const int*)d_in[7];
    float* out = (float*)d_out;

    unsigned short* xb  = (unsigned short*)d_ws;
    unsigned short* Wtq = xb  + (size_t)2048 * 1024;
    unsigned short* Wtk = Wtq + (size_t)1024 * 1024;
    unsigned short* Wtv = Wtk + (size_t)1024 * 1024;
    unsigned short* Wto = Wtv + (size_t)1024 * 1024;
    unsigned short* qh  = Wto + (size_t)1024 * 1024;   // [H][S][64]
    unsigned short* kh  = qh  + (size_t)2048 * 1024;
    unsigned short* vh  = kh  + (size_t)2048 * 1024;
    unsigned short* att = vh  + (size_t)2048 * 1024;   // [S][H*D]

    prep<<<2048, 256, 0, stream>>>(x, xb, Wq, Wk, Wv, Wo, Wtq, Wtk, Wtv, Wto);
    gemm_qkv<<<dim3(24, 32), 256, 0, stream>>>(xb, Wtq, Wtk, Wtv,
                                               qh, kh, vh, cs, sn);
    attn_kernel<<<(S_LEN * NH) / 4, 256, 0, stream>>>(qh, kh, vh, anc, att);
    gemm_out<<<dim3(16, 32), 256, 0, stream>>>(att, Wto, out);
}